// Round 3
// baseline (1262.029 us; speedup 1.0000x reference)
//
#include <hip/hip_runtime.h>
#include <cstdint>
#include <cstddef>
#include <cmath>

// Problem constants (match reference)
constexpr int Nn = 50000;
constexpr int Ne = 500000;
constexpr int Gg = 64;
constexpr int DIN = 128, ED = 32, H1 = 256, H2 = 128, HD = 64, NOUT = 8;

// ---------------- CSR build ----------------
__global__ void count_deg_kernel(const int* __restrict__ dst, int* __restrict__ deg) {
    int e = blockIdx.x * 256 + threadIdx.x;
    if (e < Ne) atomicAdd(&deg[dst[e]], 1);
}

__global__ __launch_bounds__(1024) void scan_kernel(const int* __restrict__ deg,
                                                    int* __restrict__ row_start) {
    __shared__ int part[1024];
    int t = threadIdx.x;
    const int chunk = (Nn + 1023) / 1024;
    int lo = t * chunk;
    int hi = min(lo + chunk, Nn);
    int s = 0;
    for (int i = lo; i < hi; i++) s += deg[i];
    part[t] = s;
    __syncthreads();
    for (int off = 1; off < 1024; off <<= 1) {
        int add = (t >= off) ? part[t - off] : 0;
        __syncthreads();
        part[t] += add;
        __syncthreads();
    }
    int base = (t == 0) ? 0 : part[t - 1];
    for (int i = lo; i < hi; i++) { row_start[i] = base; base += deg[i]; }
    if (t == 0) row_start[Nn] = Ne;
}

__global__ void scatter_kernel(const int* __restrict__ dst, const int* __restrict__ row_start,
                               int* __restrict__ cursor, int* __restrict__ perm) {
    int e = blockIdx.x * 256 + threadIdx.x;
    if (e < Ne) {
        int d = dst[e];
        int p = atomicAdd(&cursor[d], 1);
        perm[row_start[d] + p] = e;
    }
}

__global__ void build_sd_kernel(const int* __restrict__ perm, const int* __restrict__ src,
                                const int* __restrict__ dst,
                                int* __restrict__ srcv, int* __restrict__ dstv) {
    int j = blockIdx.x * 256 + threadIdx.x;
    if (j < Ne) {
        int e = perm[j];
        srcv[j] = src[e];
        dstv[j] = dst[e];
    }
}

// loop_attr[i] = mean of incoming edge_attr rows (self-loop fill_value='mean')
__global__ void loop_attr_kernel(const int* __restrict__ row_start, const int* __restrict__ perm,
                                 const float* __restrict__ eattr, float* __restrict__ loop_attr) {
    int tid = blockIdx.x * 256 + threadIdx.x;
    if (tid >= Nn * 8) return;
    int i = tid >> 3, q = (tid & 7) << 2;
    int r0 = row_start[i], r1 = row_start[i + 1];
    float4 s = make_float4(0.f, 0.f, 0.f, 0.f);
    for (int j = r0; j < r1; j++) {
        int e = perm[j];
        float4 v = *(const float4*)(eattr + (size_t)e * ED + q);
        s.x += v.x; s.y += v.y; s.z += v.z; s.w += v.w;
    }
    float inv = 1.0f / fmaxf((float)(r1 - r0), 1.0f);
    *(float4*)(loop_attr + (size_t)i * ED + q) =
        make_float4(s.x * inv, s.y * inv, s.z * inv, s.w * inv);
}

// ---------------- fp32 GEMM with K-chunk register double-buffer (kept from R9: helped) ----
__global__ __launch_bounds__(256) void gemm_bias2_kernel(const float* __restrict__ A,
                                                         const float* __restrict__ W0,
                                                         const float* __restrict__ bias0,
                                                         float* __restrict__ C0,
                                                         const float* __restrict__ W1,
                                                         const float* __restrict__ bias1,
                                                         float* __restrict__ C1,
                                                         int M, int K, int Ncols) {
    const float* W = blockIdx.z ? W1 : W0;
    const float* bias = blockIdx.z ? bias1 : bias0;
    float* C = blockIdx.z ? C1 : C0;
    __shared__ float As[16][68];  // [k][m], padded
    __shared__ float Bs[16][68];  // [k][n], padded
    const int m0 = blockIdx.y * 64, n0 = blockIdx.x * 64;
    const int tid = threadIdx.x;
    const int tx = tid & 15, ty = tid >> 4;
    float acc[4][4] = {};
    const int ar = tid >> 2, ac4 = (tid & 3) << 2;
    const int br = tid >> 4, bc4 = (tid & 15) << 2;
    const bool arow_ok = (m0 + ar < M);

    float4 av = make_float4(0.f, 0.f, 0.f, 0.f);
    if (arow_ok) av = *(const float4*)(A + (size_t)(m0 + ar) * K + ac4);
    float4 bv = *(const float4*)(W + (size_t)br * Ncols + n0 + bc4);

    for (int k0 = 0; k0 < K; k0 += 16) {
        As[ac4 + 0][ar] = av.x; As[ac4 + 1][ar] = av.y;
        As[ac4 + 2][ar] = av.z; As[ac4 + 3][ar] = av.w;
        *(float4*)&Bs[br][bc4] = bv;
        __syncthreads();
        // prefetch next chunk behind the FMA loop
        if (k0 + 16 < K) {
            if (arow_ok) av = *(const float4*)(A + (size_t)(m0 + ar) * K + k0 + 16 + ac4);
            bv = *(const float4*)(W + (size_t)(k0 + 16 + br) * Ncols + n0 + bc4);
        }
#pragma unroll
        for (int k = 0; k < 16; k++) {
            float a[4], b[4];
#pragma unroll
            for (int i = 0; i < 4; i++) a[i] = As[k][ty * 4 + i];
#pragma unroll
            for (int j = 0; j < 4; j++) b[j] = Bs[k][tx * 4 + j];
#pragma unroll
            for (int i = 0; i < 4; i++)
#pragma unroll
                for (int j = 0; j < 4; j++) acc[i][j] = fmaf(a[i], b[j], acc[i][j]);
        }
        __syncthreads();
    }
#pragma unroll
    for (int i = 0; i < 4; i++) {
        int m = m0 + ty * 4 + i;
        if (m < M) {
            float4 o;
            o.x = acc[i][0] + bias[n0 + tx * 4 + 0];
            o.y = acc[i][1] + bias[n0 + tx * 4 + 1];
            o.z = acc[i][2] + bias[n0 + tx * 4 + 2];
            o.w = acc[i][3] + bias[n0 + tx * 4 + 3];
            *(float4*)(C + (size_t)m * Ncols + n0 + tx * 4) = o;
        }
    }
}

// ---------------- fused GATv2: score + online-softmax + aggregate, one wave per node ------
// R11 theory: score kernel (v2/v5 both ~144us) is NOT LDS-BW-bound (v5 relieved it, no
// gain) -- it is bound by the scattered xl/xr gathers + 2x VALU overhead, and the pipeline
// gathers xl[src] TWICE (score + aggregate) plus a scores round-trip. Fuse everything:
// one wave per dst node walks its CSR row with online softmax. We (32xC) lives in per-lane
// REGISTERS (lane owns CPL=C/64 cols -> 32*CPL VGPR), so the per-edge GEMM is pure
// register FMA, zero LDS. eattr row loads are wave-uniform (HW broadcast). Ping-pong
// prefetch (A/B) hides the ~300cyc L2 gather latency behind the 128-fmac GEMM.
// Self-loop folded in via m=-inf init (exp(-inf)=0 makes process() a pure init).
// VGPR budget: 128 wreg + 64 ea(A+B) + ~40 misc ~= 230 < 256 -- no spill (R1 lesson:
// watch WRITE_SIZE; no min-waves clause in launch_bounds).
template <int C>
__global__ __launch_bounds__(256) void fused_gat_kernel(
    const int* __restrict__ row_start, const int* __restrict__ srcv,
    const int* __restrict__ perm,
    const float* __restrict__ eattr, const float* __restrict__ loop_attr,
    const float* __restrict__ xl, const float* __restrict__ xr,
    const float* __restrict__ We, const float* __restrict__ att,
    const float* __restrict__ bias, float* __restrict__ xout) {
    constexpr int CPL = C / 64;  // cols per lane: 4 (C=256) or 2 (C=128)
    const int wave = threadIdx.x >> 6, lane = threadIdx.x & 63;
    const int i = blockIdx.x * 4 + wave;
    if (i >= Nn) return;
    const int c0 = lane * CPL;

    // We column slice -> registers (static-indexed via full unroll)
    float wreg[ED][CPL];
#pragma unroll
    for (int k = 0; k < ED; k++) {
        if constexpr (CPL == 4) {
            float4 v = *(const float4*)(We + (size_t)k * C + c0);
            wreg[k][0] = v.x; wreg[k][1] = v.y; wreg[k][2] = v.z; wreg[k][3] = v.w;
        } else {
            float2 v = *(const float2*)(We + (size_t)k * C + c0);
            wreg[k][0] = v.x; wreg[k][1] = v.y;
        }
    }
    float attv[CPL];
#pragma unroll
    for (int c = 0; c < CPL; c++) attv[c] = att[c0 + c];

    const int r0 = row_start[i], r1 = row_start[i + 1];

    auto load_x = [&](const float* rowbase, float (&xs)[CPL]) {
        if constexpr (CPL == 4) {
            float4 v = *(const float4*)(rowbase + c0);
            xs[0] = v.x; xs[1] = v.y; xs[2] = v.z; xs[3] = v.w;
        } else {
            float2 v = *(const float2*)(rowbase + c0);
            xs[0] = v.x; xs[1] = v.y;
        }
    };
    auto load_ea = [&](const float* rowbase, float4 (&ea)[8]) {
#pragma unroll
        for (int q = 0; q < 8; q++) ea[q] = *(const float4*)(rowbase + q * 4);
    };

    float xri[CPL];
    load_x(xr + (size_t)i * C, xri);

    float m = -INFINITY, l = 0.f;
    float acc[CPL] = {};

    // one edge's full update: GEMM(32xCPL) -> score -> wave reduce -> online softmax
    auto process = [&](const float4 (&ea)[8], const float (&xls)[CPL]) {
        float ew[CPL] = {};
#pragma unroll
        for (int q = 0; q < 8; q++) {
            const float eak[4] = {ea[q].x, ea[q].y, ea[q].z, ea[q].w};
#pragma unroll
            for (int t = 0; t < 4; t++)
#pragma unroll
                for (int c = 0; c < CPL; c++)
                    ew[c] = fmaf(eak[t], wreg[q * 4 + t][c], ew[c]);
        }
        float pp = 0.f;
#pragma unroll
        for (int c = 0; c < CPL; c++) {
            float v = ew[c] + xls[c] + xri[c];
            v = v > 0.f ? v : 0.2f * v;
            pp = fmaf(v, attv[c], pp);
        }
        pp += __shfl_xor(pp, 1);  pp += __shfl_xor(pp, 2);
        pp += __shfl_xor(pp, 4);  pp += __shfl_xor(pp, 8);
        pp += __shfl_xor(pp, 16); pp += __shfl_xor(pp, 32);
        float mn = fmaxf(m, pp);
        float sc = __expf(m - mn);      // first call: exp(-inf)=0 -> pure init
        float w  = __expf(pp - mn);
        l = fmaf(l, sc, w);
#pragma unroll
        for (int c = 0; c < CPL; c++) acc[c] = fmaf(acc[c], sc, w * xls[c]);
        m = mn;
    };

    // ---- self-loop (src = dst = i, eattr = loop_attr[i]) ----
    {
        float xli[CPL];
        load_x(xl + (size_t)i * C, xli);
        float4 eaS[8];
        load_ea(loop_attr + (size_t)i * ED, eaS);
        process(eaS, xli);
    }

    // ---- incoming edges, ping-pong prefetched ----
    float4 eaA[8], eaB[8];
    float xlA[CPL], xlB[CPL];
    auto load_edge = [&](int j, float4 (&ea)[8], float (&xs)[CPL]) {
        int e = perm[j];
        int s = srcv[j];
        load_ea(eattr + (size_t)e * ED, ea);
        load_x(xl + (size_t)s * C, xs);
    };
    if (r0 < r1) load_edge(r0, eaA, xlA);
    for (int j = r0; j < r1; j += 2) {
        const bool hasB = (j + 1 < r1);
        if (hasB) load_edge(j + 1, eaB, xlB);
        process(eaA, xlA);
        if (hasB) {
            if (j + 2 < r1) load_edge(j + 2, eaA, xlA);
            process(eaB, xlB);
        }
    }

    // ---- normalize + bias + relu + store ----
    float invl = 1.0f / l;
    float* xo = xout + (size_t)i * C + c0;
    if constexpr (CPL == 4) {
        float4 bv = *(const float4*)(bias + c0);
        float4 o;
        o.x = fmaxf(fmaf(acc[0], invl, bv.x), 0.f);
        o.y = fmaxf(fmaf(acc[1], invl, bv.y), 0.f);
        o.z = fmaxf(fmaf(acc[2], invl, bv.z), 0.f);
        o.w = fmaxf(fmaf(acc[3], invl, bv.w), 0.f);
        *(float4*)xo = o;
    } else {
        float2 bv = *(const float2*)(bias + c0);
        float2 o;
        o.x = fmaxf(fmaf(acc[0], invl, bv.x), 0.f);
        o.y = fmaxf(fmaf(acc[1], invl, bv.y), 0.f);
        *(float2*)xo = o;
    }
}

// ---------------- global mean pool: run-length accumulation (batch is sorted) -------------
__global__ __launch_bounds__(128) void pool2_kernel(const float* __restrict__ x2,
                                                    const int* __restrict__ batch,
                                                    float* __restrict__ pooled,
                                                    float* __restrict__ cnt) {
    const int c = threadIdx.x;  // column 0..127
    const int chunk = (Nn + gridDim.x - 1) / gridDim.x;
    int lo = blockIdx.x * chunk;
    int hi = min(lo + chunk, Nn);
    if (lo >= hi) return;
    int gcur = batch[lo];
    float acc = 0.f, ncnt = 0.f;
    for (int i = lo; i < hi; i++) {
        int g = batch[i];
        if (g != gcur) {
            atomicAdd(&pooled[gcur * H2 + c], acc);
            if (c == 0) atomicAdd(&cnt[gcur], ncnt);
            acc = 0.f; ncnt = 0.f; gcur = g;
        }
        acc += x2[(size_t)i * H2 + c];
        ncnt += 1.f;
    }
    atomicAdd(&pooled[gcur * H2 + c], acc);
    if (c == 0) atomicAdd(&cnt[gcur], ncnt);
}

// ---------------- MLP head ----------------
__global__ __launch_bounds__(64) void head_kernel(
    const float* __restrict__ pooled, const float* __restrict__ cnt,
    const float* __restrict__ Wd1, const float* __restrict__ bd1,
    const float* __restrict__ gamma, const float* __restrict__ beta,
    const float* __restrict__ mean, const float* __restrict__ var,
    const float* __restrict__ Wd2, const float* __restrict__ bd2,
    float* __restrict__ out) {
    __shared__ float xm[H2];
    __shared__ float h[HD];
    int g = blockIdx.x, t = threadIdx.x;
    float c = fmaxf(cnt[g], 1.0f);
    for (int i = t; i < H2; i += 64) xm[i] = pooled[g * H2 + i] / c;
    __syncthreads();
    float a = bd1[t];
    for (int k = 0; k < H2; k++) a = fmaf(xm[k], Wd1[k * HD + t], a);
    a = (a - mean[t]) / sqrtf(var[t] + 1e-5f) * gamma[t] + beta[t];
    a = a > 0.f ? a : 0.1f * a;
    h[t] = a;
    __syncthreads();
    if (t < NOUT) {
        float o = bd2[t];
        for (int k = 0; k < HD; k++) o = fmaf(h[k], Wd2[k * NOUT + t], o);
        out[g * NOUT + t] = o;
    }
}

extern "C" void kernel_launch(void* const* d_in, const int* in_sizes, int n_in,
                              void* d_out, int out_size, void* d_ws, size_t ws_size,
                              hipStream_t stream) {
    const float* node_attr = (const float*)d_in[0];
    const float* edge_attr = (const float*)d_in[1];
    const int* edge_src = (const int*)d_in[2];
    const int* edge_dst = (const int*)d_in[3];
    const int* batch = (const int*)d_in[4];
    const float* Wl1 = (const float*)d_in[5];  const float* bl1 = (const float*)d_in[6];
    const float* Wr1 = (const float*)d_in[7];  const float* br1 = (const float*)d_in[8];
    const float* We1 = (const float*)d_in[9];  const float* att1 = (const float*)d_in[10];
    const float* b1 = (const float*)d_in[11];
    const float* Wl2 = (const float*)d_in[12]; const float* bl2 = (const float*)d_in[13];
    const float* Wr2 = (const float*)d_in[14]; const float* br2 = (const float*)d_in[15];
    const float* We2 = (const float*)d_in[16]; const float* att2 = (const float*)d_in[17];
    const float* b2 = (const float*)d_in[18];
    const float* Wd1 = (const float*)d_in[19]; const float* bd1 = (const float*)d_in[20];
    const float* bn_gamma = (const float*)d_in[21]; const float* bn_beta = (const float*)d_in[22];
    const float* bn_mean = (const float*)d_in[23];  const float* bn_var = (const float*)d_in[24];
    const float* Wd2 = (const float*)d_in[25]; const float* bd2 = (const float*)d_in[26];
    float* out = (float*)d_out;

    char* ws = (char*)d_ws;
    size_t off = 0;
    auto alloc = [&](size_t bytes) -> char* {
        char* p = ws + off;
        off = (off + bytes + 255) & ~(size_t)255;
        return p;
    };
    int* deg         = (int*)alloc((size_t)Nn * 4);
    int* row_start   = (int*)alloc((size_t)(Nn + 1) * 4);
    int* cursor      = (int*)alloc((size_t)Nn * 4);
    int* perm        = (int*)alloc((size_t)Ne * 4);
    int* srcv        = (int*)alloc((size_t)Ne * 4);
    int* dstv        = (int*)alloc((size_t)Ne * 4);
    float* loop_attr = (float*)alloc((size_t)Nn * ED * 4);
    float* pooled    = (float*)alloc((size_t)Gg * H2 * 4);
    float* cnt       = (float*)alloc((size_t)Gg * 4);
    float* xlb       = (float*)alloc((size_t)Nn * H1 * 4);
    float* xrb       = (float*)alloc((size_t)Nn * H1 * 4);
    float* x1        = (float*)alloc((size_t)Nn * H1 * 4);

    hipMemsetAsync(deg, 0, (size_t)Nn * 4, stream);
    hipMemsetAsync(cursor, 0, (size_t)Nn * 4, stream);
    hipMemsetAsync(pooled, 0, (size_t)Gg * H2 * 4, stream);
    hipMemsetAsync(cnt, 0, (size_t)Gg * 4, stream);

    count_deg_kernel<<<(Ne + 255) / 256, 256, 0, stream>>>(edge_dst, deg);
    scan_kernel<<<1, 1024, 0, stream>>>(deg, row_start);
    scatter_kernel<<<(Ne + 255) / 256, 256, 0, stream>>>(edge_dst, row_start, cursor, perm);
    build_sd_kernel<<<(Ne + 255) / 256, 256, 0, stream>>>(perm, edge_src, edge_dst, srcv, dstv);
    loop_attr_kernel<<<(Nn * 8 + 255) / 256, 256, 0, stream>>>(row_start, perm, edge_attr, loop_attr);

    const int fb = (Nn + 3) / 4;

    // ---- layer 1 ----
    gemm_bias2_kernel<<<dim3(H1 / 64, (Nn + 63) / 64, 2), 256, 0, stream>>>(
        node_attr, Wl1, bl1, xlb, Wr1, br1, xrb, Nn, DIN, H1);
    fused_gat_kernel<H1><<<fb, 256, 0, stream>>>(
        row_start, srcv, perm, edge_attr, loop_attr, xlb, xrb, We1, att1, b1, x1);

    // ---- layer 2 ----
    gemm_bias2_kernel<<<dim3(H2 / 64, (Nn + 63) / 64, 2), 256, 0, stream>>>(
        x1, Wl2, bl2, xlb, Wr2, br2, xrb, Nn, H1, H2);
    float* x2 = x1;
    fused_gat_kernel<H2><<<fb, 256, 0, stream>>>(
        row_start, srcv, perm, edge_attr, loop_attr, xlb, xrb, We2, att2, b2, x2);

    // ---- pool + head ----
    pool2_kernel<<<256, 128, 0, stream>>>(x2, batch, pooled, cnt);
    head_kernel<<<Gg, 64, 0, stream>>>(pooled, cnt, Wd1, bd1, bn_gamma, bn_beta,
                                       bn_mean, bn_var, Wd2, bd2, out);
}

// Round 4
// 1079.418 us; speedup vs baseline: 1.1692x; 1.1692x over previous
//
#include <hip/hip_runtime.h>
#include <cstdint>
#include <cstddef>
#include <cmath>

// Problem constants (match reference)
constexpr int Nn = 50000;
constexpr int Ne = 500000;
constexpr int Gg = 64;
constexpr int DIN = 128, ED = 32, H1 = 256, H2 = 128, HD = 64, NOUT = 8;

typedef __attribute__((ext_vector_type(8))) short bf16x8;
typedef __attribute__((ext_vector_type(4))) float f32x4;

__device__ __forceinline__ unsigned short f2bf(float x) {
    unsigned u = __float_as_uint(x);
    u += 0x7FFFu + ((u >> 16) & 1u);
    return (unsigned short)(u >> 16);
}
__device__ __forceinline__ float bf2f(unsigned short h) {
    return __uint_as_float(((unsigned)h) << 16);
}

// ---------------- CSR build ----------------
__global__ void count_deg_kernel(const int* __restrict__ dst, int* __restrict__ deg) {
    int e = blockIdx.x * 256 + threadIdx.x;
    if (e < Ne) atomicAdd(&deg[dst[e]], 1);
}

__global__ __launch_bounds__(1024) void scan_kernel(const int* __restrict__ deg,
                                                    int* __restrict__ row_start) {
    __shared__ int part[1024];
    int t = threadIdx.x;
    const int chunk = (Nn + 1023) / 1024;
    int lo = t * chunk;
    int hi = min(lo + chunk, Nn);
    int s = 0;
    for (int i = lo; i < hi; i++) s += deg[i];
    part[t] = s;
    __syncthreads();
    for (int off = 1; off < 1024; off <<= 1) {
        int add = (t >= off) ? part[t - off] : 0;
        __syncthreads();
        part[t] += add;
        __syncthreads();
    }
    int base = (t == 0) ? 0 : part[t - 1];
    for (int i = lo; i < hi; i++) { row_start[i] = base; base += deg[i]; }
    if (t == 0) row_start[Nn] = Ne;
}

__global__ void scatter_kernel(const int* __restrict__ dst, const int* __restrict__ row_start,
                               int* __restrict__ cursor, int* __restrict__ perm) {
    int e = blockIdx.x * 256 + threadIdx.x;
    if (e < Ne) {
        int d = dst[e];
        int p = atomicAdd(&cursor[d], 1);
        perm[row_start[d] + p] = e;
    }
}

__global__ void build_sd_kernel(const int* __restrict__ perm, const int* __restrict__ src,
                                const int* __restrict__ dst,
                                int* __restrict__ srcv, int* __restrict__ dstv) {
    int j = blockIdx.x * 256 + threadIdx.x;
    if (j < Ne) {
        int e = perm[j];
        srcv[j] = src[e];
        dstv[j] = dst[e];
    }
}

// loop_attr[i] = mean of incoming edge_attr rows (self-loop fill_value='mean')
__global__ void loop_attr_kernel(const int* __restrict__ row_start, const int* __restrict__ perm,
                                 const float* __restrict__ eattr, float* __restrict__ loop_attr) {
    int tid = blockIdx.x * 256 + threadIdx.x;
    if (tid >= Nn * 8) return;
    int i = tid >> 3, q = (tid & 7) << 2;
    int r0 = row_start[i], r1 = row_start[i + 1];
    float4 s = make_float4(0.f, 0.f, 0.f, 0.f);
    for (int j = r0; j < r1; j++) {
        int e = perm[j];
        float4 v = *(const float4*)(eattr + (size_t)e * ED + q);
        s.x += v.x; s.y += v.y; s.z += v.z; s.w += v.w;
    }
    float inv = 1.0f / fmaxf((float)(r1 - r0), 1.0f);
    *(float4*)(loop_attr + (size_t)i * ED + q) =
        make_float4(s.x * inv, s.y * inv, s.z * inv, s.w * inv);
}

// ---------------- bf16 hi/lo split prep (for MFMA score GEMM) ----------------
// hi = RN_bf16(x), lo = RN_bf16(x - hi): A*B ~ AhBh + AhBl + AlBh, err ~1e-5 rel.
__global__ void cvt_split_kernel(const float* __restrict__ src,
                                 unsigned short* __restrict__ hi,
                                 unsigned short* __restrict__ lo, int n4) {
    int idx = blockIdx.x * 256 + threadIdx.x;
    if (idx >= n4) return;
    float4 v = *(const float4*)(src + (size_t)idx * 4);
    float x[4] = {v.x, v.y, v.z, v.w};
    unsigned short h[4], l[4];
#pragma unroll
    for (int c = 0; c < 4; c++) {
        h[c] = f2bf(x[c]);
        l[c] = f2bf(x[c] - bf2f(h[c]));
    }
    *(ushort4*)(hi + (size_t)idx * 4) = make_ushort4(h[0], h[1], h[2], h[3]);
    *(ushort4*)(lo + (size_t)idx * 4) = make_ushort4(l[0], l[1], l[2], l[3]);
}

// We[32][C] -> Wt[C][32] bf16 hi/lo (transposed so B-fragments read 16B contiguous k)
__global__ void cvt_W_kernel(const float* __restrict__ We,
                             unsigned short* __restrict__ whi,
                             unsigned short* __restrict__ wlo, int C) {
    int t = blockIdx.x * 256 + threadIdx.x;
    if (t >= C * ED) return;
    int c = t >> 5, k = t & 31;
    float x = We[(size_t)k * C + c];
    unsigned short h = f2bf(x);
    whi[t] = h;
    wlo[t] = f2bf(x - bf2f(h));
}

// ---------------- fp32 GEMM with K-chunk register double-buffer (kept from R9: helped) ----
__global__ __launch_bounds__(256) void gemm_bias2_kernel(const float* __restrict__ A,
                                                         const float* __restrict__ W0,
                                                         const float* __restrict__ bias0,
                                                         float* __restrict__ C0,
                                                         const float* __restrict__ W1,
                                                         const float* __restrict__ bias1,
                                                         float* __restrict__ C1,
                                                         int M, int K, int Ncols) {
    const float* W = blockIdx.z ? W1 : W0;
    const float* bias = blockIdx.z ? bias1 : bias0;
    float* C = blockIdx.z ? C1 : C0;
    __shared__ float As[16][68];  // [k][m], padded
    __shared__ float Bs[16][68];  // [k][n], padded
    const int m0 = blockIdx.y * 64, n0 = blockIdx.x * 64;
    const int tid = threadIdx.x;
    const int tx = tid & 15, ty = tid >> 4;
    float acc[4][4] = {};
    const int ar = tid >> 2, ac4 = (tid & 3) << 2;
    const int br = tid >> 4, bc4 = (tid & 15) << 2;
    const bool arow_ok = (m0 + ar < M);

    float4 av = make_float4(0.f, 0.f, 0.f, 0.f);
    if (arow_ok) av = *(const float4*)(A + (size_t)(m0 + ar) * K + ac4);
    float4 bv = *(const float4*)(W + (size_t)br * Ncols + n0 + bc4);

    for (int k0 = 0; k0 < K; k0 += 16) {
        As[ac4 + 0][ar] = av.x; As[ac4 + 1][ar] = av.y;
        As[ac4 + 2][ar] = av.z; As[ac4 + 3][ar] = av.w;
        *(float4*)&Bs[br][bc4] = bv;
        __syncthreads();
        // prefetch next chunk behind the FMA loop
        if (k0 + 16 < K) {
            if (arow_ok) av = *(const float4*)(A + (size_t)(m0 + ar) * K + k0 + 16 + ac4);
            bv = *(const float4*)(W + (size_t)(k0 + 16 + br) * Ncols + n0 + bc4);
        }
#pragma unroll
        for (int k = 0; k < 16; k++) {
            float a[4], b[4];
#pragma unroll
            for (int i = 0; i < 4; i++) a[i] = As[k][ty * 4 + i];
#pragma unroll
            for (int j = 0; j < 4; j++) b[j] = Bs[k][tx * 4 + j];
#pragma unroll
            for (int i = 0; i < 4; i++)
#pragma unroll
                for (int j = 0; j < 4; j++) acc[i][j] = fmaf(a[i], b[j], acc[i][j]);
        }
        __syncthreads();
    }
#pragma unroll
    for (int i = 0; i < 4; i++) {
        int m = m0 + ty * 4 + i;
        if (m < M) {
            float4 o;
            o.x = acc[i][0] + bias[n0 + tx * 4 + 0];
            o.y = acc[i][1] + bias[n0 + tx * 4 + 1];
            o.z = acc[i][2] + bias[n0 + tx * 4 + 2];
            o.w = acc[i][3] + bias[n0 + tx * 4 + 3];
            *(float4*)(C + (size_t)m * Ncols + n0 + tx * 4) = o;
        }
    }
}

// ---------------- MFMA score kernel ------------------------------------------------------
// R12: score GEMM (eattr@We) moved to matrix pipe. Per 16 edges x 16 cols x k32 = 3 mfma
// (hi*hi + hi*lo + lo*hi) vs 128 VALU FMAs/edge. acc C-operand preloaded with
// xl[src]+xr[dst] in the VERIFIED C/D layout (col=lane&15, row=(lane>>4)*4+reg), so the
// gather doubles as z-init and the epilogue is just LReLU+att-dot+reduce.
// A/B frag layout (standard CDNA): A row=lane&15, B col=lane&15, k=(lane>>4)*8+j.
// (A consistent k-permutation in both A and B cancels in the dot product.)
// LDS rows padded to 40 ushorts (80B, 16B-aligned, bank stride 20 words -> 2-way = free).
template <int C>
__global__ void score_mfma_kernel(
    int count, const int* __restrict__ perm,
    const int* __restrict__ srcv, const int* __restrict__ dstv,
    const unsigned short* __restrict__ ehi, const unsigned short* __restrict__ elo,
    const float* __restrict__ xl, const float* __restrict__ xr,
    const unsigned short* __restrict__ wthi, const unsigned short* __restrict__ wtlo,
    const float* __restrict__ att, float* __restrict__ sc_out) {
    constexpr int WPB = C / 64;          // waves per block (4 for C=256, 2 for C=128)
    constexpr int NTHR = WPB * 64;
    __shared__ unsigned short Ah[64 * 40], Al[64 * 40];
    __shared__ unsigned short Bh[C * 40], Bl[C * 40];
    __shared__ float pw[WPB][64];
    const int tid = threadIdx.x;
    const int j0 = blockIdx.x * 64;

    // stage A: 64 edge rows x 32 k bf16 (hi,lo); 16B chunks
    for (int t = tid; t < 64 * 4; t += NTHR) {
        int row = t >> 2, part = t & 3;
        int j = min(j0 + row, count - 1);
        int e = perm ? perm[j] : j;
        *(uint4*)&Ah[row * 40 + part * 8] = *(const uint4*)(ehi + (size_t)e * ED + part * 8);
        *(uint4*)&Al[row * 40 + part * 8] = *(const uint4*)(elo + (size_t)e * ED + part * 8);
    }
    // stage B: Wt[C][32] bf16 (hi,lo)
    for (int t = tid; t < C * 4; t += NTHR) {
        int col = t >> 2, part = t & 3;
        *(uint4*)&Bh[col * 40 + part * 8] = *(const uint4*)(wthi + (size_t)col * ED + part * 8);
        *(uint4*)&Bl[col * 40 + part * 8] = *(const uint4*)(wtlo + (size_t)col * ED + part * 8);
    }
    __syncthreads();

    const int wv = tid >> 6, lane = tid & 63;
    const int g = lane >> 4, li = lane & 15;
    const int colbase = wv * 64 + li;

    float attv[4];
#pragma unroll
    for (int n = 0; n < 4; n++) attv[n] = att[colbase + n * 16];

    // edge row ids for this lane's acc rows: E = m*16 + g*4 + r
    int sE[4][4], dE[4][4];
#pragma unroll
    for (int m = 0; m < 4; m++)
#pragma unroll
        for (int r = 0; r < 4; r++) {
            int j = min(j0 + m * 16 + g * 4 + r, count - 1);
            sE[m][r] = srcv ? srcv[j] : j;
            dE[m][r] = dstv ? dstv[j] : j;
        }

    // acc preload: C-operand = xl[s] + xr[d] at (edge,col) in C/D layout
    f32x4 acc[4][4];
#pragma unroll
    for (int m = 0; m < 4; m++)
#pragma unroll
        for (int n = 0; n < 4; n++) {
            int col = colbase + n * 16;
#pragma unroll
            for (int r = 0; r < 4; r++)
                acc[m][n][r] = xl[(size_t)sE[m][r] * C + col] + xr[(size_t)dE[m][r] * C + col];
        }

    // fragments from LDS
    bf16x8 af_h[4], af_l[4], bf_h[4], bf_l[4];
#pragma unroll
    for (int m = 0; m < 4; m++) {
        af_h[m] = *(const bf16x8*)&Ah[(m * 16 + li) * 40 + g * 8];
        af_l[m] = *(const bf16x8*)&Al[(m * 16 + li) * 40 + g * 8];
    }
#pragma unroll
    for (int n = 0; n < 4; n++) {
        int col = colbase + n * 16;
        bf_h[n] = *(const bf16x8*)&Bh[col * 40 + g * 8];
        bf_l[n] = *(const bf16x8*)&Bl[col * 40 + g * 8];
    }

#pragma unroll
    for (int m = 0; m < 4; m++)
#pragma unroll
        for (int n = 0; n < 4; n++) {
            acc[m][n] = __builtin_amdgcn_mfma_f32_16x16x32_bf16(af_h[m], bf_h[n], acc[m][n], 0, 0, 0);
            acc[m][n] = __builtin_amdgcn_mfma_f32_16x16x32_bf16(af_h[m], bf_l[n], acc[m][n], 0, 0, 0);
            acc[m][n] = __builtin_amdgcn_mfma_f32_16x16x32_bf16(af_l[m], bf_h[n], acc[m][n], 0, 0, 0);
        }

    // epilogue: LReLU + att-dot over this wave's 64 cols, reduce over 16-lane group
#pragma unroll
    for (int m = 0; m < 4; m++)
#pragma unroll
        for (int r = 0; r < 4; r++) {
            float s = 0.f;
#pragma unroll
            for (int n = 0; n < 4; n++) {
                float z = acc[m][n][r];
                z = z > 0.f ? z : 0.2f * z;
                s = fmaf(z, attv[n], s);
            }
            s += __shfl_xor(s, 1);
            s += __shfl_xor(s, 2);
            s += __shfl_xor(s, 4);
            s += __shfl_xor(s, 8);
            if (li == 0) pw[wv][m * 16 + g * 4 + r] = s;
        }
    __syncthreads();
    if (tid < 64) {
        float s = pw[0][tid];
#pragma unroll
        for (int w = 1; w < WPB; w++) s += pw[w][tid];
        int j = j0 + tid;
        if (j < count) sc_out[j] = s;
    }
}

// ---------------- aggregate: softmax over precomputed scores + pipelined gather ----------
template <int C>
__global__ __launch_bounds__(256) void aggregate2_kernel(
    const int* __restrict__ row_start, const int* __restrict__ srcv,
    const float* __restrict__ scores, const float* __restrict__ sscore,
    const float* __restrict__ xl, const float* __restrict__ bias,
    float* __restrict__ xout) {
    constexpr int VP = C / 64;
    const int wave = threadIdx.x >> 6, lane = threadIdx.x & 63;
    const int i = blockIdx.x * 4 + wave;
    if (i >= Nn) return;
    const int r0 = row_start[i], r1 = row_start[i + 1];

    // max over incoming + self
    float mx = sscore[i];
    for (int j = r0 + lane; j < r1; j += 64) mx = fmaxf(mx, scores[j]);
#pragma unroll
    for (int off = 32; off >= 1; off >>= 1) mx = fmaxf(mx, __shfl_xor(mx, off));

    float l = 0.f;
    float acc[VP];
#pragma unroll
    for (int j = 0; j < VP; j++) acc[j] = 0.f;

    float wA[4], xA[4][VP];
    auto load_batch = [&](int j0, float* w, float (*x)[VP]) {
#pragma unroll
        for (int q = 0; q < 4; q++) {
            int j = min(j0 + q, r1 - 1);
            w[q] = scores[j];
            const float* p = xl + (size_t)srcv[j] * C + lane * VP;
            if constexpr (VP == 4) {
                float4 v = *(const float4*)p;
                x[q][0] = v.x; x[q][1] = v.y; x[q][2] = v.z; x[q][3] = v.w;
            } else {
                float2 v = *(const float2*)p;
                x[q][0] = v.x; x[q][1] = v.y;
            }
        }
    };
    if (r0 < r1) load_batch(r0, wA, xA);

    for (int j0 = r0; j0 < r1; j0 += 4) {
        float wB[4], xB[4][VP];
        if (j0 + 4 < r1) load_batch(j0 + 4, wB, xB);  // prefetch next batch
        const int nb = min(4, r1 - j0);
        for (int q = 0; q < nb; q++) {
            float w = __expf(wA[q] - mx);
            l += w;
#pragma unroll
            for (int j = 0; j < VP; j++) acc[j] = fmaf(w, xA[q][j], acc[j]);
        }
        if (j0 + 4 < r1) {
#pragma unroll
            for (int q = 0; q < 4; q++) {
                wA[q] = wB[q];
#pragma unroll
                for (int j = 0; j < VP; j++) xA[q][j] = xB[q][j];
            }
        }
    }

    // self-loop
    {
        float w = __expf(sscore[i] - mx);
        l += w;
        const float* p = xl + (size_t)i * C + lane * VP;
        if constexpr (VP == 4) {
            float4 v = *(const float4*)p;
            acc[0] = fmaf(w, v.x, acc[0]); acc[1] = fmaf(w, v.y, acc[1]);
            acc[2] = fmaf(w, v.z, acc[2]); acc[3] = fmaf(w, v.w, acc[3]);
        } else {
            float2 v = *(const float2*)p;
            acc[0] = fmaf(w, v.x, acc[0]); acc[1] = fmaf(w, v.y, acc[1]);
        }
    }

    float invl = 1.0f / l;
    float* xo = xout + (size_t)i * C + lane * VP;
    if constexpr (VP == 4) {
        float4 bv = *(const float4*)(bias + lane * 4);
        float4 o;
        o.x = fmaxf(fmaf(acc[0], invl, bv.x), 0.f);
        o.y = fmaxf(fmaf(acc[1], invl, bv.y), 0.f);
        o.z = fmaxf(fmaf(acc[2], invl, bv.z), 0.f);
        o.w = fmaxf(fmaf(acc[3], invl, bv.w), 0.f);
        *(float4*)xo = o;
    } else {
        float2 bv = *(const float2*)(bias + lane * 2);
        float2 o;
        o.x = fmaxf(fmaf(acc[0], invl, bv.x), 0.f);
        o.y = fmaxf(fmaf(acc[1], invl, bv.y), 0.f);
        *(float2*)xo = o;
    }
}

// ---------------- global mean pool: run-length accumulation (batch is sorted) -------------
__global__ __launch_bounds__(128) void pool2_kernel(const float* __restrict__ x2,
                                                    const int* __restrict__ batch,
                                                    float* __restrict__ pooled,
                                                    float* __restrict__ cnt) {
    const int c = threadIdx.x;  // column 0..127
    const int chunk = (Nn + gridDim.x - 1) / gridDim.x;
    int lo = blockIdx.x * chunk;
    int hi = min(lo + chunk, Nn);
    if (lo >= hi) return;
    int gcur = batch[lo];
    float acc = 0.f, ncnt = 0.f;
    for (int i = lo; i < hi; i++) {
        int g = batch[i];
        if (g != gcur) {
            atomicAdd(&pooled[gcur * H2 + c], acc);
            if (c == 0) atomicAdd(&cnt[gcur], ncnt);
            acc = 0.f; ncnt = 0.f; gcur = g;
        }
        acc += x2[(size_t)i * H2 + c];
        ncnt += 1.f;
    }
    atomicAdd(&pooled[gcur * H2 + c], acc);
    if (c == 0) atomicAdd(&cnt[gcur], ncnt);
}

// ---------------- MLP head ----------------
__global__ __launch_bounds__(64) void head_kernel(
    const float* __restrict__ pooled, const float* __restrict__ cnt,
    const float* __restrict__ Wd1, const float* __restrict__ bd1,
    const float* __restrict__ gamma, const float* __restrict__ beta,
    const float* __restrict__ mean, const float* __restrict__ var,
    const float* __restrict__ Wd2, const float* __restrict__ bd2,
    float* __restrict__ out) {
    __shared__ float xm[H2];
    __shared__ float h[HD];
    int g = blockIdx.x, t = threadIdx.x;
    float c = fmaxf(cnt[g], 1.0f);
    for (int i = t; i < H2; i += 64) xm[i] = pooled[g * H2 + i] / c;
    __syncthreads();
    float a = bd1[t];
    for (int k = 0; k < H2; k++) a = fmaf(xm[k], Wd1[k * HD + t], a);
    a = (a - mean[t]) / sqrtf(var[t] + 1e-5f) * gamma[t] + beta[t];
    a = a > 0.f ? a : 0.1f * a;
    h[t] = a;
    __syncthreads();
    if (t < NOUT) {
        float o = bd2[t];
        for (int k = 0; k < HD; k++) o = fmaf(h[k], Wd2[k * NOUT + t], o);
        out[g * NOUT + t] = o;
    }
}

extern "C" void kernel_launch(void* const* d_in, const int* in_sizes, int n_in,
                              void* d_out, int out_size, void* d_ws, size_t ws_size,
                              hipStream_t stream) {
    const float* node_attr = (const float*)d_in[0];
    const float* edge_attr = (const float*)d_in[1];
    const int* edge_src = (const int*)d_in[2];
    const int* edge_dst = (const int*)d_in[3];
    const int* batch = (const int*)d_in[4];
    const float* Wl1 = (const float*)d_in[5];  const float* bl1 = (const float*)d_in[6];
    const float* Wr1 = (const float*)d_in[7];  const float* br1 = (const float*)d_in[8];
    const float* We1 = (const float*)d_in[9];  const float* att1 = (const float*)d_in[10];
    const float* b1 = (const float*)d_in[11];
    const float* Wl2 = (const float*)d_in[12]; const float* bl2 = (const float*)d_in[13];
    const float* Wr2 = (const float*)d_in[14]; const float* br2 = (const float*)d_in[15];
    const float* We2 = (const float*)d_in[16]; const float* att2 = (const float*)d_in[17];
    const float* b2 = (const float*)d_in[18];
    const float* Wd1 = (const float*)d_in[19]; const float* bd1 = (const float*)d_in[20];
    const float* bn_gamma = (const float*)d_in[21]; const float* bn_beta = (const float*)d_in[22];
    const float* bn_mean = (const float*)d_in[23];  const float* bn_var = (const float*)d_in[24];
    const float* Wd2 = (const float*)d_in[25]; const float* bd2 = (const float*)d_in[26];
    float* out = (float*)d_out;

    char* ws = (char*)d_ws;
    size_t off = 0;
    auto alloc = [&](size_t bytes) -> char* {
        char* p = ws + off;
        off = (off + bytes + 255) & ~(size_t)255;
        return p;
    };
    int* deg         = (int*)alloc((size_t)Nn * 4);
    int* row_start   = (int*)alloc((size_t)(Nn + 1) * 4);
    int* cursor      = (int*)alloc((size_t)Nn * 4);
    int* perm        = (int*)alloc((size_t)Ne * 4);
    int* srcv        = (int*)alloc((size_t)Ne * 4);
    int* dstv        = (int*)alloc((size_t)Ne * 4);
    float* loop_attr = (float*)alloc((size_t)Nn * ED * 4);
    float* scores    = (float*)alloc((size_t)Ne * 4);
    float* sscore    = (float*)alloc((size_t)Nn * 4);
    float* pooled    = (float*)alloc((size_t)Gg * H2 * 4);
    float* cnt       = (float*)alloc((size_t)Gg * 4);
    float* xlb       = (float*)alloc((size_t)Nn * H1 * 4);
    float* xrb       = (float*)alloc((size_t)Nn * H1 * 4);
    float* x1        = (float*)alloc((size_t)Nn * H1 * 4);
    unsigned short* ehi = (unsigned short*)alloc((size_t)Ne * ED * 2);
    unsigned short* elo = (unsigned short*)alloc((size_t)Ne * ED * 2);
    unsigned short* lhi = (unsigned short*)alloc((size_t)Nn * ED * 2);
    unsigned short* llo = (unsigned short*)alloc((size_t)Nn * ED * 2);
    unsigned short* w1hi = (unsigned short*)alloc((size_t)H1 * ED * 2);
    unsigned short* w1lo = (unsigned short*)alloc((size_t)H1 * ED * 2);
    unsigned short* w2hi = (unsigned short*)alloc((size_t)H2 * ED * 2);
    unsigned short* w2lo = (unsigned short*)alloc((size_t)H2 * ED * 2);

    hipMemsetAsync(deg, 0, (size_t)Nn * 4, stream);
    hipMemsetAsync(cursor, 0, (size_t)Nn * 4, stream);
    hipMemsetAsync(pooled, 0, (size_t)Gg * H2 * 4, stream);
    hipMemsetAsync(cnt, 0, (size_t)Gg * 4, stream);

    count_deg_kernel<<<(Ne + 255) / 256, 256, 0, stream>>>(edge_dst, deg);
    scan_kernel<<<1, 1024, 0, stream>>>(deg, row_start);
    scatter_kernel<<<(Ne + 255) / 256, 256, 0, stream>>>(edge_dst, row_start, cursor, perm);
    build_sd_kernel<<<(Ne + 255) / 256, 256, 0, stream>>>(perm, edge_src, edge_dst, srcv, dstv);
    loop_attr_kernel<<<(Nn * 8 + 255) / 256, 256, 0, stream>>>(row_start, perm, edge_attr, loop_attr);

    // bf16 hi/lo prep
    cvt_split_kernel<<<(Ne * 8 + 255) / 256, 256, 0, stream>>>(edge_attr, ehi, elo, Ne * 8);
    cvt_split_kernel<<<(Nn * 8 + 255) / 256, 256, 0, stream>>>(loop_attr, lhi, llo, Nn * 8);
    cvt_W_kernel<<<(H1 * ED + 255) / 256, 256, 0, stream>>>(We1, w1hi, w1lo, H1);
    cvt_W_kernel<<<(H2 * ED + 255) / 256, 256, 0, stream>>>(We2, w2hi, w2lo, H2);

    const int eb64 = (Ne + 63) / 64, nb64 = (Nn + 63) / 64;

    // ---- layer 1 ----
    gemm_bias2_kernel<<<dim3(H1 / 64, (Nn + 63) / 64, 2), 256, 0, stream>>>(
        node_attr, Wl1, bl1, xlb, Wr1, br1, xrb, Nn, DIN, H1);
    score_mfma_kernel<H1><<<eb64, 256, 0, stream>>>(
        Ne, perm, srcv, dstv, ehi, elo, xlb, xrb, w1hi, w1lo, att1, scores);
    score_mfma_kernel<H1><<<nb64, 256, 0, stream>>>(
        Nn, nullptr, nullptr, nullptr, lhi, llo, xlb, xrb, w1hi, w1lo, att1, sscore);
    aggregate2_kernel<H1><<<(Nn + 3) / 4, 256, 0, stream>>>(
        row_start, srcv, scores, sscore, xlb, b1, x1);

    // ---- layer 2 ----
    gemm_bias2_kernel<<<dim3(H2 / 64, (Nn + 63) / 64, 2), 256, 0, stream>>>(
        x1, Wl2, bl2, xlb, Wr2, br2, xrb, Nn, H1, H2);
    score_mfma_kernel<H2><<<eb64, 128, 0, stream>>>(
        Ne, perm, srcv, dstv, ehi, elo, xlb, xrb, w2hi, w2lo, att2, scores);
    score_mfma_kernel<H2><<<nb64, 128, 0, stream>>>(
        Nn, nullptr, nullptr, nullptr, lhi, llo, xlb, xrb, w2hi, w2lo, att2, sscore);
    float* x2 = x1;
    aggregate2_kernel<H2><<<(Nn + 3) / 4, 256, 0, stream>>>(
        row_start, srcv, scores, sscore, xlb, b2, x2);

    // ---- pool + head ----
    pool2_kernel<<<256, 128, 0, stream>>>(x2, batch, pooled, cnt);
    head_kernel<<<Gg, 64, 0, stream>>>(pooled, cnt, Wd1, bd1, bn_gamma, bn_beta,
                                       bn_mean, bn_var, Wd2, bd2, out);
}

// Round 5
// 939.153 us; speedup vs baseline: 1.3438x; 1.1494x over previous
//
#include <hip/hip_runtime.h>
#include <cstdint>
#include <cstddef>
#include <cmath>

// Problem constants (match reference)
constexpr int Nn = 50000;
constexpr int Ne = 500000;
constexpr int Gg = 64;
constexpr int DIN = 128, ED = 32, H1 = 256, H2 = 128, HD = 64, NOUT = 8;

typedef __attribute__((ext_vector_type(8))) short bf16x8;
typedef __attribute__((ext_vector_type(4))) float f32x4;

__device__ __forceinline__ unsigned short f2bf(float x) {
    unsigned u = __float_as_uint(x);
    u += 0x7FFFu + ((u >> 16) & 1u);
    return (unsigned short)(u >> 16);
}
__device__ __forceinline__ float bf2f(unsigned short h) {
    return __uint_as_float(((unsigned)h) << 16);
}

// ---------------- CSR build ----------------
__global__ void count_deg_kernel(const int* __restrict__ dst, int* __restrict__ deg) {
    int e = blockIdx.x * 256 + threadIdx.x;
    if (e < Ne) atomicAdd(&deg[dst[e]], 1);
}

__global__ __launch_bounds__(1024) void scan_kernel(const int* __restrict__ deg,
                                                    int* __restrict__ row_start) {
    __shared__ int part[1024];
    int t = threadIdx.x;
    const int chunk = (Nn + 1023) / 1024;
    int lo = t * chunk;
    int hi = min(lo + chunk, Nn);
    int s = 0;
    for (int i = lo; i < hi; i++) s += deg[i];
    part[t] = s;
    __syncthreads();
    for (int off = 1; off < 1024; off <<= 1) {
        int add = (t >= off) ? part[t - off] : 0;
        __syncthreads();
        part[t] += add;
        __syncthreads();
    }
    int base = (t == 0) ? 0 : part[t - 1];
    for (int i = lo; i < hi; i++) { row_start[i] = base; base += deg[i]; }
    if (t == 0) row_start[Nn] = Ne;
}

__global__ void scatter_kernel(const int* __restrict__ dst, const int* __restrict__ row_start,
                               int* __restrict__ cursor, int* __restrict__ perm) {
    int e = blockIdx.x * 256 + threadIdx.x;
    if (e < Ne) {
        int d = dst[e];
        int p = atomicAdd(&cursor[d], 1);
        perm[row_start[d] + p] = e;
    }
}

__global__ void build_sd_kernel(const int* __restrict__ perm, const int* __restrict__ src,
                                const int* __restrict__ dst,
                                int* __restrict__ srcv, int* __restrict__ dstv) {
    int j = blockIdx.x * 256 + threadIdx.x;
    if (j < Ne) {
        int e = perm[j];
        srcv[j] = src[e];
        dstv[j] = dst[e];
    }
}

// loop_attr[i] = mean of incoming edge_attr rows (self-loop fill_value='mean')
__global__ void loop_attr_kernel(const int* __restrict__ row_start, const int* __restrict__ perm,
                                 const float* __restrict__ eattr, float* __restrict__ loop_attr) {
    int tid = blockIdx.x * 256 + threadIdx.x;
    if (tid >= Nn * 8) return;
    int i = tid >> 3, q = (tid & 7) << 2;
    int r0 = row_start[i], r1 = row_start[i + 1];
    float4 s = make_float4(0.f, 0.f, 0.f, 0.f);
    for (int j = r0; j < r1; j++) {
        int e = perm[j];
        float4 v = *(const float4*)(eattr + (size_t)e * ED + q);
        s.x += v.x; s.y += v.y; s.z += v.z; s.w += v.w;
    }
    float inv = 1.0f / fmaxf((float)(r1 - r0), 1.0f);
    *(float4*)(loop_attr + (size_t)i * ED + q) =
        make_float4(s.x * inv, s.y * inv, s.z * inv, s.w * inv);
}

// ---------------- bf16 hi/lo split prep (for MFMA score GEMM) ----------------
// hi = RN_bf16(x), lo = RN_bf16(x - hi): A*B ~ AhBh + AhBl + AlBh, err ~1e-5 rel.
__global__ void cvt_split_kernel(const float* __restrict__ src,
                                 unsigned short* __restrict__ hi,
                                 unsigned short* __restrict__ lo, int n4) {
    int idx = blockIdx.x * 256 + threadIdx.x;
    if (idx >= n4) return;
    float4 v = *(const float4*)(src + (size_t)idx * 4);
    float x[4] = {v.x, v.y, v.z, v.w};
    unsigned short h[4], l[4];
#pragma unroll
    for (int c = 0; c < 4; c++) {
        h[c] = f2bf(x[c]);
        l[c] = f2bf(x[c] - bf2f(h[c]));
    }
    *(ushort4*)(hi + (size_t)idx * 4) = make_ushort4(h[0], h[1], h[2], h[3]);
    *(ushort4*)(lo + (size_t)idx * 4) = make_ushort4(l[0], l[1], l[2], l[3]);
}

// We[32][C] -> Wt[C][32] bf16 hi/lo (transposed so A-fragments read 16B contiguous k)
__global__ void cvt_W_kernel(const float* __restrict__ We,
                             unsigned short* __restrict__ whi,
                             unsigned short* __restrict__ wlo, int C) {
    int t = blockIdx.x * 256 + threadIdx.x;
    if (t >= C * ED) return;
    int c = t >> 5, k = t & 31;
    float x = We[(size_t)k * C + c];
    unsigned short h = f2bf(x);
    whi[t] = h;
    wlo[t] = f2bf(x - bf2f(h));
}

// ---------------- fp32 GEMM with K-chunk register double-buffer (kept from R9: helped) ----
__global__ __launch_bounds__(256) void gemm_bias2_kernel(const float* __restrict__ A,
                                                         const float* __restrict__ W0,
                                                         const float* __restrict__ bias0,
                                                         float* __restrict__ C0,
                                                         const float* __restrict__ W1,
                                                         const float* __restrict__ bias1,
                                                         float* __restrict__ C1,
                                                         int M, int K, int Ncols) {
    const float* W = blockIdx.z ? W1 : W0;
    const float* bias = blockIdx.z ? bias1 : bias0;
    float* C = blockIdx.z ? C1 : C0;
    __shared__ float As[16][68];  // [k][m], padded
    __shared__ float Bs[16][68];  // [k][n], padded
    const int m0 = blockIdx.y * 64, n0 = blockIdx.x * 64;
    const int tid = threadIdx.x;
    const int tx = tid & 15, ty = tid >> 4;
    float acc[4][4] = {};
    const int ar = tid >> 2, ac4 = (tid & 3) << 2;
    const int br = tid >> 4, bc4 = (tid & 15) << 2;
    const bool arow_ok = (m0 + ar < M);

    float4 av = make_float4(0.f, 0.f, 0.f, 0.f);
    if (arow_ok) av = *(const float4*)(A + (size_t)(m0 + ar) * K + ac4);
    float4 bv = *(const float4*)(W + (size_t)br * Ncols + n0 + bc4);

    for (int k0 = 0; k0 < K; k0 += 16) {
        As[ac4 + 0][ar] = av.x; As[ac4 + 1][ar] = av.y;
        As[ac4 + 2][ar] = av.z; As[ac4 + 3][ar] = av.w;
        *(float4*)&Bs[br][bc4] = bv;
        __syncthreads();
        // prefetch next chunk behind the FMA loop
        if (k0 + 16 < K) {
            if (arow_ok) av = *(const float4*)(A + (size_t)(m0 + ar) * K + k0 + 16 + ac4);
            bv = *(const float4*)(W + (size_t)(k0 + 16 + br) * Ncols + n0 + bc4);
        }
#pragma unroll
        for (int k = 0; k < 16; k++) {
            float a[4], b[4];
#pragma unroll
            for (int i = 0; i < 4; i++) a[i] = As[k][ty * 4 + i];
#pragma unroll
            for (int j = 0; j < 4; j++) b[j] = Bs[k][tx * 4 + j];
#pragma unroll
            for (int i = 0; i < 4; i++)
#pragma unroll
                for (int j = 0; j < 4; j++) acc[i][j] = fmaf(a[i], b[j], acc[i][j]);
        }
        __syncthreads();
    }
#pragma unroll
    for (int i = 0; i < 4; i++) {
        int m = m0 + ty * 4 + i;
        if (m < M) {
            float4 o;
            o.x = acc[i][0] + bias[n0 + tx * 4 + 0];
            o.y = acc[i][1] + bias[n0 + tx * 4 + 1];
            o.z = acc[i][2] + bias[n0 + tx * 4 + 2];
            o.w = acc[i][3] + bias[n0 + tx * 4 + 3];
            *(float4*)(C + (size_t)m * Ncols + n0 + tx * 4) = o;
        }
    }
}

// ---------------- MFMA score kernel v2 (operand swap + no spill) --------------------------
// R13 post-mortem of v1: (a) missing __launch_bounds__ -> hipcc assumed 1024-thr blocks ->
//     64-VGPR cap -> 100MB scratch spill (VGPR_Count=64, WRITE_SIZE 103MB). (b) edges on
//     the M axis made the xl/xr C-preload 128 SCALAR loads/lane (acc rows = 4 different
//     edges). v2 swaps operands: A = Wt (M = We-cols), B = eattr (N = edges). Per lane:
//     one edge per n-tile, acc's 4 regs = 4 CONSECUTIVE cols -> float4 xl/xr preload.
// D layout (m89-verified): col(N)=lane&15 -> edge=li; row(M)=(lane>>4)*4+reg -> We-col.
// A frag: row=li, k=(lane>>4)*8+j -> Wt[col][g*8..] read DIRECT from global (L1-resident,
//     no LDS). B frag: col=li, k=g*8+j -> Ah[(n*16+li)*40 + g*8] from LDS (edge rows
//     gathered via perm; staged coalesced). LDS 11KB (was 52KB). n-loop keeps acc[4] live
//     (16 regs) instead of acc[4][4]; peak ~120 VGPR under explicit launch_bounds(NTHR).
template <int C>
__global__ __launch_bounds__((C / 64) * 64) void score_mfma2_kernel(
    int count, const int* __restrict__ perm,
    const int* __restrict__ srcv, const int* __restrict__ dstv,
    const unsigned short* __restrict__ ehi, const unsigned short* __restrict__ elo,
    const float* __restrict__ xl, const float* __restrict__ xr,
    const unsigned short* __restrict__ wthi, const unsigned short* __restrict__ wtlo,
    const float* __restrict__ att, float* __restrict__ sc_out) {
    constexpr int WPB = C / 64;          // waves per block (4 for C=256, 2 for C=128)
    constexpr int NTHR = WPB * 64;
    __shared__ unsigned short Ah[64 * 40], Al[64 * 40];  // pitch 40 ush = 80B, 16B-aligned
    __shared__ float pw[WPB][64];
    const int tid = threadIdx.x;
    const int j0 = blockIdx.x * 64;

    // stage 64 edge rows x 32 k bf16 (hi,lo) into LDS, coalesced 16B chunks
    for (int t = tid; t < 64 * 4; t += NTHR) {
        int row = t >> 2, part = t & 3;
        int j = min(j0 + row, count - 1);
        int e = perm ? perm[j] : j;
        *(uint4*)&Ah[row * 40 + part * 8] = *(const uint4*)(ehi + (size_t)e * ED + part * 8);
        *(uint4*)&Al[row * 40 + part * 8] = *(const uint4*)(elo + (size_t)e * ED + part * 8);
    }
    __syncthreads();

    const int wv = tid >> 6, lane = tid & 63;
    const int g = lane >> 4, li = lane & 15;
    const int cb = wv * 64 + g * 4;      // lane's col base (plus m*16)

    // A operand: Wt column fragments, straight from global (tiny, L1-hot)
    bf16x8 af_h[4], af_l[4];
#pragma unroll
    for (int m = 0; m < 4; m++) {
        int col = wv * 64 + m * 16 + li;
        af_h[m] = *(const bf16x8*)(wthi + (size_t)col * ED + g * 8);
        af_l[m] = *(const bf16x8*)(wtlo + (size_t)col * ED + g * 8);
    }
    float4 attv[4];
#pragma unroll
    for (int m = 0; m < 4; m++) attv[m] = *(const float4*)(att + cb + m * 16);

#pragma unroll 2
    for (int n = 0; n < 4; n++) {
        int j = min(j0 + n * 16 + li, count - 1);
        int sE = srcv ? srcv[j] : j;
        int dE = dstv ? dstv[j] : j;
        // B operand: this lane's edge row, k-slice g
        bf16x8 bf_h = *(const bf16x8*)&Ah[(n * 16 + li) * 40 + g * 8];
        bf16x8 bf_l = *(const bf16x8*)&Al[(n * 16 + li) * 40 + g * 8];
        // acc preload: C-op = xl[sE][col] + xr[dE][col], col = cb + m*16 + r (float4!)
        f32x4 acc[4];
#pragma unroll
        for (int m = 0; m < 4; m++) {
            float4 a4 = *(const float4*)(xl + (size_t)sE * C + cb + m * 16);
            float4 b4 = *(const float4*)(xr + (size_t)dE * C + cb + m * 16);
            acc[m][0] = a4.x + b4.x; acc[m][1] = a4.y + b4.y;
            acc[m][2] = a4.z + b4.z; acc[m][3] = a4.w + b4.w;
        }
#pragma unroll
        for (int m = 0; m < 4; m++) {
            acc[m] = __builtin_amdgcn_mfma_f32_16x16x32_bf16(af_h[m], bf_h, acc[m], 0, 0, 0);
            acc[m] = __builtin_amdgcn_mfma_f32_16x16x32_bf16(af_h[m], bf_l, acc[m], 0, 0, 0);
            acc[m] = __builtin_amdgcn_mfma_f32_16x16x32_bf16(af_l[m], bf_h, acc[m], 0, 0, 0);
        }
        // epilogue: LReLU + att-dot over this lane's 16 cols, then reduce across g-groups
        float s = 0.f;
#pragma unroll
        for (int m = 0; m < 4; m++) {
            const float av[4] = {attv[m].x, attv[m].y, attv[m].z, attv[m].w};
#pragma unroll
            for (int r = 0; r < 4; r++) {
                float z = acc[m][r];
                z = z > 0.f ? z : 0.2f * z;
                s = fmaf(z, av[r], s);
            }
        }
        s += __shfl_xor(s, 16);
        s += __shfl_xor(s, 32);
        if (lane < 16) pw[wv][n * 16 + li] = s;
    }
    __syncthreads();
    if (tid < 64) {
        float s = pw[0][tid];
#pragma unroll
        for (int w = 1; w < WPB; w++) s += pw[w][tid];
        int j = j0 + tid;
        if (j < count) sc_out[j] = s;
    }
}

// ---------------- aggregate: softmax over precomputed scores + pipelined gather ----------
template <int C>
__global__ __launch_bounds__(256) void aggregate2_kernel(
    const int* __restrict__ row_start, const int* __restrict__ srcv,
    const float* __restrict__ scores, const float* __restrict__ sscore,
    const float* __restrict__ xl, const float* __restrict__ bias,
    float* __restrict__ xout) {
    constexpr int VP = C / 64;
    const int wave = threadIdx.x >> 6, lane = threadIdx.x & 63;
    const int i = blockIdx.x * 4 + wave;
    if (i >= Nn) return;
    const int r0 = row_start[i], r1 = row_start[i + 1];

    // max over incoming + self
    float mx = sscore[i];
    for (int j = r0 + lane; j < r1; j += 64) mx = fmaxf(mx, scores[j]);
#pragma unroll
    for (int off = 32; off >= 1; off >>= 1) mx = fmaxf(mx, __shfl_xor(mx, off));

    float l = 0.f;
    float acc[VP];
#pragma unroll
    for (int j = 0; j < VP; j++) acc[j] = 0.f;

    float wA[4], xA[4][VP];
    auto load_batch = [&](int j0, float* w, float (*x)[VP]) {
#pragma unroll
        for (int q = 0; q < 4; q++) {
            int j = min(j0 + q, r1 - 1);
            w[q] = scores[j];
            const float* p = xl + (size_t)srcv[j] * C + lane * VP;
            if constexpr (VP == 4) {
                float4 v = *(const float4*)p;
                x[q][0] = v.x; x[q][1] = v.y; x[q][2] = v.z; x[q][3] = v.w;
            } else {
                float2 v = *(const float2*)p;
                x[q][0] = v.x; x[q][1] = v.y;
            }
        }
    };
    if (r0 < r1) load_batch(r0, wA, xA);

    for (int j0 = r0; j0 < r1; j0 += 4) {
        float wB[4], xB[4][VP];
        if (j0 + 4 < r1) load_batch(j0 + 4, wB, xB);  // prefetch next batch
        const int nb = min(4, r1 - j0);
        for (int q = 0; q < nb; q++) {
            float w = __expf(wA[q] - mx);
            l += w;
#pragma unroll
            for (int j = 0; j < VP; j++) acc[j] = fmaf(w, xA[q][j], acc[j]);
        }
        if (j0 + 4 < r1) {
#pragma unroll
            for (int q = 0; q < 4; q++) {
                wA[q] = wB[q];
#pragma unroll
                for (int j = 0; j < VP; j++) xA[q][j] = xB[q][j];
            }
        }
    }

    // self-loop
    {
        float w = __expf(sscore[i] - mx);
        l += w;
        const float* p = xl + (size_t)i * C + lane * VP;
        if constexpr (VP == 4) {
            float4 v = *(const float4*)p;
            acc[0] = fmaf(w, v.x, acc[0]); acc[1] = fmaf(w, v.y, acc[1]);
            acc[2] = fmaf(w, v.z, acc[2]); acc[3] = fmaf(w, v.w, acc[3]);
        } else {
            float2 v = *(const float2*)p;
            acc[0] = fmaf(w, v.x, acc[0]); acc[1] = fmaf(w, v.y, acc[1]);
        }
    }

    float invl = 1.0f / l;
    float* xo = xout + (size_t)i * C + lane * VP;
    if constexpr (VP == 4) {
        float4 bv = *(const float4*)(bias + lane * 4);
        float4 o;
        o.x = fmaxf(fmaf(acc[0], invl, bv.x), 0.f);
        o.y = fmaxf(fmaf(acc[1], invl, bv.y), 0.f);
        o.z = fmaxf(fmaf(acc[2], invl, bv.z), 0.f);
        o.w = fmaxf(fmaf(acc[3], invl, bv.w), 0.f);
        *(float4*)xo = o;
    } else {
        float2 bv = *(const float2*)(bias + lane * 2);
        float2 o;
        o.x = fmaxf(fmaf(acc[0], invl, bv.x), 0.f);
        o.y = fmaxf(fmaf(acc[1], invl, bv.y), 0.f);
        *(float2*)xo = o;
    }
}

// ---------------- global mean pool: run-length accumulation (batch is sorted) -------------
__global__ __launch_bounds__(128) void pool2_kernel(const float* __restrict__ x2,
                                                    const int* __restrict__ batch,
                                                    float* __restrict__ pooled,
                                                    float* __restrict__ cnt) {
    const int c = threadIdx.x;  // column 0..127
    const int chunk = (Nn + gridDim.x - 1) / gridDim.x;
    int lo = blockIdx.x * chunk;
    int hi = min(lo + chunk, Nn);
    if (lo >= hi) return;
    int gcur = batch[lo];
    float acc = 0.f, ncnt = 0.f;
    for (int i = lo; i < hi; i++) {
        int g = batch[i];
        if (g != gcur) {
            atomicAdd(&pooled[gcur * H2 + c], acc);
            if (c == 0) atomicAdd(&cnt[gcur], ncnt);
            acc = 0.f; ncnt = 0.f; gcur = g;
        }
        acc += x2[(size_t)i * H2 + c];
        ncnt += 1.f;
    }
    atomicAdd(&pooled[gcur * H2 + c], acc);
    if (c == 0) atomicAdd(&cnt[gcur], ncnt);
}

// ---------------- MLP head ----------------
__global__ __launch_bounds__(64) void head_kernel(
    const float* __restrict__ pooled, const float* __restrict__ cnt,
    const float* __restrict__ Wd1, const float* __restrict__ bd1,
    const float* __restrict__ gamma, const float* __restrict__ beta,
    const float* __restrict__ mean, const float* __restrict__ var,
    const float* __restrict__ Wd2, const float* __restrict__ bd2,
    float* __restrict__ out) {
    __shared__ float xm[H2];
    __shared__ float h[HD];
    int g = blockIdx.x, t = threadIdx.x;
    float c = fmaxf(cnt[g], 1.0f);
    for (int i = t; i < H2; i += 64) xm[i] = pooled[g * H2 + i] / c;
    __syncthreads();
    float a = bd1[t];
    for (int k = 0; k < H2; k++) a = fmaf(xm[k], Wd1[k * HD + t], a);
    a = (a - mean[t]) / sqrtf(var[t] + 1e-5f) * gamma[t] + beta[t];
    a = a > 0.f ? a : 0.1f * a;
    h[t] = a;
    __syncthreads();
    if (t < NOUT) {
        float o = bd2[t];
        for (int k = 0; k < HD; k++) o = fmaf(h[k], Wd2[k * NOUT + t], o);
        out[g * NOUT + t] = o;
    }
}

extern "C" void kernel_launch(void* const* d_in, const int* in_sizes, int n_in,
                              void* d_out, int out_size, void* d_ws, size_t ws_size,
                              hipStream_t stream) {
    const float* node_attr = (const float*)d_in[0];
    const float* edge_attr = (const float*)d_in[1];
    const int* edge_src = (const int*)d_in[2];
    const int* edge_dst = (const int*)d_in[3];
    const int* batch = (const int*)d_in[4];
    const float* Wl1 = (const float*)d_in[5];  const float* bl1 = (const float*)d_in[6];
    const float* Wr1 = (const float*)d_in[7];  const float* br1 = (const float*)d_in[8];
    const float* We1 = (const float*)d_in[9];  const float* att1 = (const float*)d_in[10];
    const float* b1 = (const float*)d_in[11];
    const float* Wl2 = (const float*)d_in[12]; const float* bl2 = (const float*)d_in[13];
    const float* Wr2 = (const float*)d_in[14]; const float* br2 = (const float*)d_in[15];
    const float* We2 = (const float*)d_in[16]; const float* att2 = (const float*)d_in[17];
    const float* b2 = (const float*)d_in[18];
    const float* Wd1 = (const float*)d_in[19]; const float* bd1 = (const float*)d_in[20];
    const float* bn_gamma = (const float*)d_in[21]; const float* bn_beta = (const float*)d_in[22];
    const float* bn_mean = (const float*)d_in[23];  const float* bn_var = (const float*)d_in[24];
    const float* Wd2 = (const float*)d_in[25]; const float* bd2 = (const float*)d_in[26];
    float* out = (float*)d_out;

    char* ws = (char*)d_ws;
    size_t off = 0;
    auto alloc = [&](size_t bytes) -> char* {
        char* p = ws + off;
        off = (off + bytes + 255) & ~(size_t)255;
        return p;
    };
    int* deg         = (int*)alloc((size_t)Nn * 4);
    int* row_start   = (int*)alloc((size_t)(Nn + 1) * 4);
    int* cursor      = (int*)alloc((size_t)Nn * 4);
    int* perm        = (int*)alloc((size_t)Ne * 4);
    int* srcv        = (int*)alloc((size_t)Ne * 4);
    int* dstv        = (int*)alloc((size_t)Ne * 4);
    float* loop_attr = (float*)alloc((size_t)Nn * ED * 4);
    float* scores    = (float*)alloc((size_t)Ne * 4);
    float* sscore    = (float*)alloc((size_t)Nn * 4);
    float* pooled    = (float*)alloc((size_t)Gg * H2 * 4);
    float* cnt       = (float*)alloc((size_t)Gg * 4);
    float* xlb       = (float*)alloc((size_t)Nn * H1 * 4);
    float* xrb       = (float*)alloc((size_t)Nn * H1 * 4);
    float* x1        = (float*)alloc((size_t)Nn * H1 * 4);
    unsigned short* ehi = (unsigned short*)alloc((size_t)Ne * ED * 2);
    unsigned short* elo = (unsigned short*)alloc((size_t)Ne * ED * 2);
    unsigned short* lhi = (unsigned short*)alloc((size_t)Nn * ED * 2);
    unsigned short* llo = (unsigned short*)alloc((size_t)Nn * ED * 2);
    unsigned short* w1hi = (unsigned short*)alloc((size_t)H1 * ED * 2);
    unsigned short* w1lo = (unsigned short*)alloc((size_t)H1 * ED * 2);
    unsigned short* w2hi = (unsigned short*)alloc((size_t)H2 * ED * 2);
    unsigned short* w2lo = (unsigned short*)alloc((size_t)H2 * ED * 2);

    hipMemsetAsync(deg, 0, (size_t)Nn * 4, stream);
    hipMemsetAsync(cursor, 0, (size_t)Nn * 4, stream);
    hipMemsetAsync(pooled, 0, (size_t)Gg * H2 * 4, stream);
    hipMemsetAsync(cnt, 0, (size_t)Gg * 4, stream);

    count_deg_kernel<<<(Ne + 255) / 256, 256, 0, stream>>>(edge_dst, deg);
    scan_kernel<<<1, 1024, 0, stream>>>(deg, row_start);
    scatter_kernel<<<(Ne + 255) / 256, 256, 0, stream>>>(edge_dst, row_start, cursor, perm);
    build_sd_kernel<<<(Ne + 255) / 256, 256, 0, stream>>>(perm, edge_src, edge_dst, srcv, dstv);
    loop_attr_kernel<<<(Nn * 8 + 255) / 256, 256, 0, stream>>>(row_start, perm, edge_attr, loop_attr);

    // bf16 hi/lo prep
    cvt_split_kernel<<<(Ne * 8 + 255) / 256, 256, 0, stream>>>(edge_attr, ehi, elo, Ne * 8);
    cvt_split_kernel<<<(Nn * 8 + 255) / 256, 256, 0, stream>>>(loop_attr, lhi, llo, Nn * 8);
    cvt_W_kernel<<<(H1 * ED + 255) / 256, 256, 0, stream>>>(We1, w1hi, w1lo, H1);
    cvt_W_kernel<<<(H2 * ED + 255) / 256, 256, 0, stream>>>(We2, w2hi, w2lo, H2);

    const int eb64 = (Ne + 63) / 64, nb64 = (Nn + 63) / 64;

    // ---- layer 1 ----
    gemm_bias2_kernel<<<dim3(H1 / 64, (Nn + 63) / 64, 2), 256, 0, stream>>>(
        node_attr, Wl1, bl1, xlb, Wr1, br1, xrb, Nn, DIN, H1);
    score_mfma2_kernel<H1><<<eb64, 256, 0, stream>>>(
        Ne, perm, srcv, dstv, ehi, elo, xlb, xrb, w1hi, w1lo, att1, scores);
    score_mfma2_kernel<H1><<<nb64, 256, 0, stream>>>(
        Nn, nullptr, nullptr, nullptr, lhi, llo, xlb, xrb, w1hi, w1lo, att1, sscore);
    aggregate2_kernel<H1><<<(Nn + 3) / 4, 256, 0, stream>>>(
        row_start, srcv, scores, sscore, xlb, b1, x1);

    // ---- layer 2 ----
    gemm_bias2_kernel<<<dim3(H2 / 64, (Nn + 63) / 64, 2), 256, 0, stream>>>(
        x1, Wl2, bl2, xlb, Wr2, br2, xrb, Nn, H1, H2);
    score_mfma2_kernel<H2><<<eb64, 128, 0, stream>>>(
        Ne, perm, srcv, dstv, ehi, elo, xlb, xrb, w2hi, w2lo, att2, scores);
    score_mfma2_kernel<H2><<<nb64, 128, 0, stream>>>(
        Nn, nullptr, nullptr, nullptr, lhi, llo, xlb, xrb, w2hi, w2lo, att2, sscore);
    float* x2 = x1;
    aggregate2_kernel<H2><<<(Nn + 3) / 4, 256, 0, stream>>>(
        row_start, srcv, scores, sscore, xlb, b2, x2);

    // ---- pool + head ----
    pool2_kernel<<<256, 128, 0, stream>>>(x2, batch, pooled, cnt);
    head_kernel<<<Gg, 64, 0, stream>>>(pooled, cnt, Wd1, bd1, bn_gamma, bn_beta,
                                       bn_mean, bn_var, Wd2, bd2, out);
}

// Round 6
// 919.774 us; speedup vs baseline: 1.3721x; 1.0211x over previous
//
#include <hip/hip_runtime.h>
#include <cstdint>
#include <cstddef>
#include <cmath>

// Problem constants (match reference)
constexpr int Nn = 50000;
constexpr int Ne = 500000;
constexpr int Gg = 64;
constexpr int DIN = 128, ED = 32, H1 = 256, H2 = 128, HD = 64, NOUT = 8;

typedef __attribute__((ext_vector_type(8))) short bf16x8;
typedef __attribute__((ext_vector_type(4))) float f32x4;

__device__ __forceinline__ unsigned short f2bf(float x) {
    unsigned u = __float_as_uint(x);
    u += 0x7FFFu + ((u >> 16) & 1u);
    return (unsigned short)(u >> 16);
}
__device__ __forceinline__ float bf2f(unsigned short h) {
    return __uint_as_float(((unsigned)h) << 16);
}

// ---------------- CSR build ----------------
__global__ void count_deg_kernel(const int* __restrict__ dst, int* __restrict__ deg) {
    int e = blockIdx.x * 256 + threadIdx.x;
    if (e < Ne) atomicAdd(&deg[dst[e]], 1);
}

__global__ __launch_bounds__(1024) void scan_kernel(const int* __restrict__ deg,
                                                    int* __restrict__ row_start) {
    __shared__ int part[1024];
    int t = threadIdx.x;
    const int chunk = (Nn + 1023) / 1024;
    int lo = t * chunk;
    int hi = min(lo + chunk, Nn);
    int s = 0;
    for (int i = lo; i < hi; i++) s += deg[i];
    part[t] = s;
    __syncthreads();
    for (int off = 1; off < 1024; off <<= 1) {
        int add = (t >= off) ? part[t - off] : 0;
        __syncthreads();
        part[t] += add;
        __syncthreads();
    }
    int base = (t == 0) ? 0 : part[t - 1];
    for (int i = lo; i < hi; i++) { row_start[i] = base; base += deg[i]; }
    if (t == 0) row_start[Nn] = Ne;
}

__global__ void scatter_kernel(const int* __restrict__ dst, const int* __restrict__ row_start,
                               int* __restrict__ cursor, int* __restrict__ perm) {
    int e = blockIdx.x * 256 + threadIdx.x;
    if (e < Ne) {
        int d = dst[e];
        int p = atomicAdd(&cursor[d], 1);
        perm[row_start[d] + p] = e;
    }
}

__global__ void build_sd_kernel(const int* __restrict__ perm, const int* __restrict__ src,
                                const int* __restrict__ dst,
                                int* __restrict__ srcv, int* __restrict__ dstv) {
    int j = blockIdx.x * 256 + threadIdx.x;
    if (j < Ne) {
        int e = perm[j];
        srcv[j] = src[e];
        dstv[j] = dst[e];
    }
}

// loop_attr[i] = mean of incoming edge_attr rows (self-loop fill_value='mean')
__global__ void loop_attr_kernel(const int* __restrict__ row_start, const int* __restrict__ perm,
                                 const float* __restrict__ eattr, float* __restrict__ loop_attr) {
    int tid = blockIdx.x * 256 + threadIdx.x;
    if (tid >= Nn * 8) return;
    int i = tid >> 3, q = (tid & 7) << 2;
    int r0 = row_start[i], r1 = row_start[i + 1];
    float4 s = make_float4(0.f, 0.f, 0.f, 0.f);
    for (int j = r0; j < r1; j++) {
        int e = perm[j];
        float4 v = *(const float4*)(eattr + (size_t)e * ED + q);
        s.x += v.x; s.y += v.y; s.z += v.z; s.w += v.w;
    }
    float inv = 1.0f / fmaxf((float)(r1 - r0), 1.0f);
    *(float4*)(loop_attr + (size_t)i * ED + q) =
        make_float4(s.x * inv, s.y * inv, s.z * inv, s.w * inv);
}

// ---------------- bf16 hi/lo split prep (for MFMA score GEMM) ----------------
// hi = RN_bf16(x), lo = RN_bf16(x - hi): A*B ~ AhBh + AhBl + AlBh, err ~1e-5 rel.
__global__ void cvt_split_kernel(const float* __restrict__ src,
                                 unsigned short* __restrict__ hi,
                                 unsigned short* __restrict__ lo, int n4) {
    int idx = blockIdx.x * 256 + threadIdx.x;
    if (idx >= n4) return;
    float4 v = *(const float4*)(src + (size_t)idx * 4);
    float x[4] = {v.x, v.y, v.z, v.w};
    unsigned short h[4], l[4];
#pragma unroll
    for (int c = 0; c < 4; c++) {
        h[c] = f2bf(x[c]);
        l[c] = f2bf(x[c] - bf2f(h[c]));
    }
    *(ushort4*)(hi + (size_t)idx * 4) = make_ushort4(h[0], h[1], h[2], h[3]);
    *(ushort4*)(lo + (size_t)idx * 4) = make_ushort4(l[0], l[1], l[2], l[3]);
}

// We[32][C] -> Wt[C][32] bf16 hi/lo (transposed so A-fragments read 16B contiguous k)
__global__ void cvt_W_kernel(const float* __restrict__ We,
                             unsigned short* __restrict__ whi,
                             unsigned short* __restrict__ wlo, int C) {
    int t = blockIdx.x * 256 + threadIdx.x;
    if (t >= C * ED) return;
    int c = t >> 5, k = t & 31;
    float x = We[(size_t)k * C + c];
    unsigned short h = f2bf(x);
    whi[t] = h;
    wlo[t] = f2bf(x - bf2f(h));
}

// ---------------- fp32 GEMM with K-chunk register double-buffer (kept from R9: helped) ----
__global__ __launch_bounds__(256) void gemm_bias2_kernel(const float* __restrict__ A,
                                                         const float* __restrict__ W0,
                                                         const float* __restrict__ bias0,
                                                         float* __restrict__ C0,
                                                         const float* __restrict__ W1,
                                                         const float* __restrict__ bias1,
                                                         float* __restrict__ C1,
                                                         int M, int K, int Ncols) {
    const float* W = blockIdx.z ? W1 : W0;
    const float* bias = blockIdx.z ? bias1 : bias0;
    float* C = blockIdx.z ? C1 : C0;
    __shared__ float As[16][68];  // [k][m], padded
    __shared__ float Bs[16][68];  // [k][n], padded
    const int m0 = blockIdx.y * 64, n0 = blockIdx.x * 64;
    const int tid = threadIdx.x;
    const int tx = tid & 15, ty = tid >> 4;
    float acc[4][4] = {};
    const int ar = tid >> 2, ac4 = (tid & 3) << 2;
    const int br = tid >> 4, bc4 = (tid & 15) << 2;
    const bool arow_ok = (m0 + ar < M);

    float4 av = make_float4(0.f, 0.f, 0.f, 0.f);
    if (arow_ok) av = *(const float4*)(A + (size_t)(m0 + ar) * K + ac4);
    float4 bv = *(const float4*)(W + (size_t)br * Ncols + n0 + bc4);

    for (int k0 = 0; k0 < K; k0 += 16) {
        As[ac4 + 0][ar] = av.x; As[ac4 + 1][ar] = av.y;
        As[ac4 + 2][ar] = av.z; As[ac4 + 3][ar] = av.w;
        *(float4*)&Bs[br][bc4] = bv;
        __syncthreads();
        // prefetch next chunk behind the FMA loop
        if (k0 + 16 < K) {
            if (arow_ok) av = *(const float4*)(A + (size_t)(m0 + ar) * K + k0 + 16 + ac4);
            bv = *(const float4*)(W + (size_t)(k0 + 16 + br) * Ncols + n0 + bc4);
        }
#pragma unroll
        for (int k = 0; k < 16; k++) {
            float a[4], b[4];
#pragma unroll
            for (int i = 0; i < 4; i++) a[i] = As[k][ty * 4 + i];
#pragma unroll
            for (int j = 0; j < 4; j++) b[j] = Bs[k][tx * 4 + j];
#pragma unroll
            for (int i = 0; i < 4; i++)
#pragma unroll
                for (int j = 0; j < 4; j++) acc[i][j] = fmaf(a[i], b[j], acc[i][j]);
        }
        __syncthreads();
    }
#pragma unroll
    for (int i = 0; i < 4; i++) {
        int m = m0 + ty * 4 + i;
        if (m < M) {
            float4 o;
            o.x = acc[i][0] + bias[n0 + tx * 4 + 0];
            o.y = acc[i][1] + bias[n0 + tx * 4 + 1];
            o.z = acc[i][2] + bias[n0 + tx * 4 + 2];
            o.w = acc[i][3] + bias[n0 + tx * 4 + 3];
            *(float4*)(C + (size_t)m * Ncols + n0 + tx * 4) = o;
        }
    }
}

// ---------------- MFMA score kernel v3: 2-deep software-pipelined gathers -----------------
// R14: v2 was latency-bound (118us vs 52us BW floor; VALUBusy 25%, MfmaUtil 8%, no
// resource limit at VGPR 60 / Occ 40%): per n-tile the srcv->xl-gather->MFMA chain was
// serial with only one tile's loads in flight. v3: explicit 2-deep ping-pong (A/B register
// sets, static-indexed per scratch rule; edge indices hoisted as scalars for all 4 tiles):
//   pf(0,A); pf(1,B); comp(0,A); pf(2,A); comp(1,B); pf(3,B); comp(2,A); comp(3,B);
// Each pf = 2 LDS frag reads + 8 float4 gathers; gathers for tile n+2 overlap ~2 compute
// phases (~600cyc) covering L2 (~200) and most HBM (~900) latency. ~170 VGPR -> same
// 3 waves/SIMD as measured. Tripwire: WRITE_SIZE must stay ~2MB (spill detector).
template <int C>
__global__ __launch_bounds__((C / 64) * 64) void score_mfma3_kernel(
    int count, const int* __restrict__ perm,
    const int* __restrict__ srcv, const int* __restrict__ dstv,
    const unsigned short* __restrict__ ehi, const unsigned short* __restrict__ elo,
    const float* __restrict__ xl, const float* __restrict__ xr,
    const unsigned short* __restrict__ wthi, const unsigned short* __restrict__ wtlo,
    const float* __restrict__ att, float* __restrict__ sc_out) {
    constexpr int WPB = C / 64;          // waves per block (4 for C=256, 2 for C=128)
    constexpr int NTHR = WPB * 64;
    __shared__ unsigned short Ah[64 * 40], Al[64 * 40];  // pitch 40 ush = 80B, 16B-aligned
    __shared__ float pw[WPB][64];
    const int tid = threadIdx.x;
    const int j0 = blockIdx.x * 64;

    // stage 64 edge rows x 32 k bf16 (hi,lo) into LDS, coalesced 16B chunks
    for (int t = tid; t < 64 * 4; t += NTHR) {
        int row = t >> 2, part = t & 3;
        int j = min(j0 + row, count - 1);
        int e = perm ? perm[j] : j;
        *(uint4*)&Ah[row * 40 + part * 8] = *(const uint4*)(ehi + (size_t)e * ED + part * 8);
        *(uint4*)&Al[row * 40 + part * 8] = *(const uint4*)(elo + (size_t)e * ED + part * 8);
    }
    __syncthreads();

    const int wv = tid >> 6, lane = tid & 63;
    const int g = lane >> 4, li = lane & 15;
    const int cb = wv * 64 + g * 4;      // lane's col base (plus m*16)

    // A operand: Wt column fragments, straight from global (tiny, L1-hot)
    bf16x8 af_h[4], af_l[4];
#pragma unroll
    for (int m = 0; m < 4; m++) {
        int col = wv * 64 + m * 16 + li;
        af_h[m] = *(const bf16x8*)(wthi + (size_t)col * ED + g * 8);
        af_l[m] = *(const bf16x8*)(wtlo + (size_t)col * ED + g * 8);
    }
    float4 attv[4];
#pragma unroll
    for (int m = 0; m < 4; m++) attv[m] = *(const float4*)(att + cb + m * 16);

    // hoisted edge indices for all 4 n-tiles (scalars, no arrays -> no scratch)
    int s0, d0, s1, d1, s2, d2, s3, d3;
    {
        int j;
        j = min(j0 + 0 * 16 + li, count - 1); s0 = srcv ? srcv[j] : j; d0 = dstv ? dstv[j] : j;
        j = min(j0 + 1 * 16 + li, count - 1); s1 = srcv ? srcv[j] : j; d1 = dstv ? dstv[j] : j;
        j = min(j0 + 2 * 16 + li, count - 1); s2 = srcv ? srcv[j] : j; d2 = dstv ? dstv[j] : j;
        j = min(j0 + 3 * 16 + li, count - 1); s3 = srcv ? srcv[j] : j; d3 = dstv ? dstv[j] : j;
    }

    // prefetch: LDS B-fragments + xl/xr gathers for one tile into a named register set
    auto pf = [&](int n, int sE, int dE, bf16x8& bh, bf16x8& bl,
                  float4 (&xlv)[4], float4 (&xrv)[4]) {
        bh = *(const bf16x8*)&Ah[(n * 16 + li) * 40 + g * 8];
        bl = *(const bf16x8*)&Al[(n * 16 + li) * 40 + g * 8];
        const float* pl = xl + (size_t)sE * C + cb;
        const float* pr = xr + (size_t)dE * C + cb;
#pragma unroll
        for (int m = 0; m < 4; m++) {
            xlv[m] = *(const float4*)(pl + m * 16);
            xrv[m] = *(const float4*)(pr + m * 16);
        }
    };
    // compute: acc preload (C-op = xl+xr), 12 MFMAs, LReLU+att-dot epilogue, partial write
    auto comp = [&](int n, bf16x8 bh, bf16x8 bl,
                    const float4 (&xlv)[4], const float4 (&xrv)[4]) {
        f32x4 acc[4];
#pragma unroll
        for (int m = 0; m < 4; m++) {
            acc[m][0] = xlv[m].x + xrv[m].x; acc[m][1] = xlv[m].y + xrv[m].y;
            acc[m][2] = xlv[m].z + xrv[m].z; acc[m][3] = xlv[m].w + xrv[m].w;
        }
#pragma unroll
        for (int m = 0; m < 4; m++) {
            acc[m] = __builtin_amdgcn_mfma_f32_16x16x32_bf16(af_h[m], bh, acc[m], 0, 0, 0);
            acc[m] = __builtin_amdgcn_mfma_f32_16x16x32_bf16(af_h[m], bl, acc[m], 0, 0, 0);
            acc[m] = __builtin_amdgcn_mfma_f32_16x16x32_bf16(af_l[m], bh, acc[m], 0, 0, 0);
        }
        float s = 0.f;
#pragma unroll
        for (int m = 0; m < 4; m++) {
            const float av[4] = {attv[m].x, attv[m].y, attv[m].z, attv[m].w};
#pragma unroll
            for (int r = 0; r < 4; r++) {
                float z = acc[m][r];
                z = z > 0.f ? z : 0.2f * z;
                s = fmaf(z, av[r], s);
            }
        }
        s += __shfl_xor(s, 16);
        s += __shfl_xor(s, 32);
        if (lane < 16) pw[wv][n * 16 + li] = s;
    };

    bf16x8 bhA, blA, bhB, blB;
    float4 xlA[4], xrA[4], xlB[4], xrB[4];
    pf(0, s0, d0, bhA, blA, xlA, xrA);
    pf(1, s1, d1, bhB, blB, xlB, xrB);
    comp(0, bhA, blA, xlA, xrA);
    pf(2, s2, d2, bhA, blA, xlA, xrA);
    comp(1, bhB, blB, xlB, xrB);
    pf(3, s3, d3, bhB, blB, xlB, xrB);
    comp(2, bhA, blA, xlA, xrA);
    comp(3, bhB, blB, xlB, xrB);

    __syncthreads();
    if (tid < 64) {
        float s = pw[0][tid];
#pragma unroll
        for (int w = 1; w < WPB; w++) s += pw[w][tid];
        int j = j0 + tid;
        if (j < count) sc_out[j] = s;
    }
}

// ---------------- aggregate: softmax over precomputed scores + pipelined gather ----------
template <int C>
__global__ __launch_bounds__(256) void aggregate2_kernel(
    const int* __restrict__ row_start, const int* __restrict__ srcv,
    const float* __restrict__ scores, const float* __restrict__ sscore,
    const float* __restrict__ xl, const float* __restrict__ bias,
    float* __restrict__ xout) {
    constexpr int VP = C / 64;
    const int wave = threadIdx.x >> 6, lane = threadIdx.x & 63;
    const int i = blockIdx.x * 4 + wave;
    if (i >= Nn) return;
    const int r0 = row_start[i], r1 = row_start[i + 1];

    // max over incoming + self
    float mx = sscore[i];
    for (int j = r0 + lane; j < r1; j += 64) mx = fmaxf(mx, scores[j]);
#pragma unroll
    for (int off = 32; off >= 1; off >>= 1) mx = fmaxf(mx, __shfl_xor(mx, off));

    float l = 0.f;
    float acc[VP];
#pragma unroll
    for (int j = 0; j < VP; j++) acc[j] = 0.f;

    float wA[4], xA[4][VP];
    auto load_batch = [&](int j0, float* w, float (*x)[VP]) {
#pragma unroll
        for (int q = 0; q < 4; q++) {
            int j = min(j0 + q, r1 - 1);
            w[q] = scores[j];
            const float* p = xl + (size_t)srcv[j] * C + lane * VP;
            if constexpr (VP == 4) {
                float4 v = *(const float4*)p;
                x[q][0] = v.x; x[q][1] = v.y; x[q][2] = v.z; x[q][3] = v.w;
            } else {
                float2 v = *(const float2*)p;
                x[q][0] = v.x; x[q][1] = v.y;
            }
        }
    };
    if (r0 < r1) load_batch(r0, wA, xA);

    for (int j0 = r0; j0 < r1; j0 += 4) {
        float wB[4], xB[4][VP];
        if (j0 + 4 < r1) load_batch(j0 + 4, wB, xB);  // prefetch next batch
        const int nb = min(4, r1 - j0);
        for (int q = 0; q < nb; q++) {
            float w = __expf(wA[q] - mx);
            l += w;
#pragma unroll
            for (int j = 0; j < VP; j++) acc[j] = fmaf(w, xA[q][j], acc[j]);
        }
        if (j0 + 4 < r1) {
#pragma unroll
            for (int q = 0; q < 4; q++) {
                wA[q] = wB[q];
#pragma unroll
                for (int j = 0; j < VP; j++) xA[q][j] = xB[q][j];
            }
        }
    }

    // self-loop
    {
        float w = __expf(sscore[i] - mx);
        l += w;
        const float* p = xl + (size_t)i * C + lane * VP;
        if constexpr (VP == 4) {
            float4 v = *(const float4*)p;
            acc[0] = fmaf(w, v.x, acc[0]); acc[1] = fmaf(w, v.y, acc[1]);
            acc[2] = fmaf(w, v.z, acc[2]); acc[3] = fmaf(w, v.w, acc[3]);
        } else {
            float2 v = *(const float2*)p;
            acc[0] = fmaf(w, v.x, acc[0]); acc[1] = fmaf(w, v.y, acc[1]);
        }
    }

    float invl = 1.0f / l;
    float* xo = xout + (size_t)i * C + lane * VP;
    if constexpr (VP == 4) {
        float4 bv = *(const float4*)(bias + lane * 4);
        float4 o;
        o.x = fmaxf(fmaf(acc[0], invl, bv.x), 0.f);
        o.y = fmaxf(fmaf(acc[1], invl, bv.y), 0.f);
        o.z = fmaxf(fmaf(acc[2], invl, bv.z), 0.f);
        o.w = fmaxf(fmaf(acc[3], invl, bv.w), 0.f);
        *(float4*)xo = o;
    } else {
        float2 bv = *(const float2*)(bias + lane * 2);
        float2 o;
        o.x = fmaxf(fmaf(acc[0], invl, bv.x), 0.f);
        o.y = fmaxf(fmaf(acc[1], invl, bv.y), 0.f);
        *(float2*)xo = o;
    }
}

// ---------------- global mean pool: run-length accumulation (batch is sorted) -------------
__global__ __launch_bounds__(128) void pool2_kernel(const float* __restrict__ x2,
                                                    const int* __restrict__ batch,
                                                    float* __restrict__ pooled,
                                                    float* __restrict__ cnt) {
    const int c = threadIdx.x;  // column 0..127
    const int chunk = (Nn + gridDim.x - 1) / gridDim.x;
    int lo = blockIdx.x * chunk;
    int hi = min(lo + chunk, Nn);
    if (lo >= hi) return;
    int gcur = batch[lo];
    float acc = 0.f, ncnt = 0.f;
    for (int i = lo; i < hi; i++) {
        int g = batch[i];
        if (g != gcur) {
            atomicAdd(&pooled[gcur * H2 + c], acc);
            if (c == 0) atomicAdd(&cnt[gcur], ncnt);
            acc = 0.f; ncnt = 0.f; gcur = g;
        }
        acc += x2[(size_t)i * H2 + c];
        ncnt += 1.f;
    }
    atomicAdd(&pooled[gcur * H2 + c], acc);
    if (c == 0) atomicAdd(&cnt[gcur], ncnt);
}

// ---------------- MLP head ----------------
__global__ __launch_bounds__(64) void head_kernel(
    const float* __restrict__ pooled, const float* __restrict__ cnt,
    const float* __restrict__ Wd1, const float* __restrict__ bd1,
    const float* __restrict__ gamma, const float* __restrict__ beta,
    const float* __restrict__ mean, const float* __restrict__ var,
    const float* __restrict__ Wd2, const float* __restrict__ bd2,
    float* __restrict__ out) {
    __shared__ float xm[H2];
    __shared__ float h[HD];
    int g = blockIdx.x, t = threadIdx.x;
    float c = fmaxf(cnt[g], 1.0f);
    for (int i = t; i < H2; i += 64) xm[i] = pooled[g * H2 + i] / c;
    __syncthreads();
    float a = bd1[t];
    for (int k = 0; k < H2; k++) a = fmaf(xm[k], Wd1[k * HD + t], a);
    a = (a - mean[t]) / sqrtf(var[t] + 1e-5f) * gamma[t] + beta[t];
    a = a > 0.f ? a : 0.1f * a;
    h[t] = a;
    __syncthreads();
    if (t < NOUT) {
        float o = bd2[t];
        for (int k = 0; k < HD; k++) o = fmaf(h[k], Wd2[k * NOUT + t], o);
        out[g * NOUT + t] = o;
    }
}

extern "C" void kernel_launch(void* const* d_in, const int* in_sizes, int n_in,
                              void* d_out, int out_size, void* d_ws, size_t ws_size,
                              hipStream_t stream) {
    const float* node_attr = (const float*)d_in[0];
    const float* edge_attr = (const float*)d_in[1];
    const int* edge_src = (const int*)d_in[2];
    const int* edge_dst = (const int*)d_in[3];
    const int* batch = (const int*)d_in[4];
    const float* Wl1 = (const float*)d_in[5];  const float* bl1 = (const float*)d_in[6];
    const float* Wr1 = (const float*)d_in[7];  const float* br1 = (const float*)d_in[8];
    const float* We1 = (const float*)d_in[9];  const float* att1 = (const float*)d_in[10];
    const float* b1 = (const float*)d_in[11];
    const float* Wl2 = (const float*)d_in[12]; const float* bl2 = (const float*)d_in[13];
    const float* Wr2 = (const float*)d_in[14]; const float* br2 = (const float*)d_in[15];
    const float* We2 = (const float*)d_in[16]; const float* att2 = (const float*)d_in[17];
    const float* b2 = (const float*)d_in[18];
    const float* Wd1 = (const float*)d_in[19]; const float* bd1 = (const float*)d_in[20];
    const float* bn_gamma = (const float*)d_in[21]; const float* bn_beta = (const float*)d_in[22];
    const float* bn_mean = (const float*)d_in[23];  const float* bn_var = (const float*)d_in[24];
    const float* Wd2 = (const float*)d_in[25]; const float* bd2 = (const float*)d_in[26];
    float* out = (float*)d_out;

    char* ws = (char*)d_ws;
    size_t off = 0;
    auto alloc = [&](size_t bytes) -> char* {
        char* p = ws + off;
        off = (off + bytes + 255) & ~(size_t)255;
        return p;
    };
    int* deg         = (int*)alloc((size_t)Nn * 4);
    int* row_start   = (int*)alloc((size_t)(Nn + 1) * 4);
    int* cursor      = (int*)alloc((size_t)Nn * 4);
    int* perm        = (int*)alloc((size_t)Ne * 4);
    int* srcv        = (int*)alloc((size_t)Ne * 4);
    int* dstv        = (int*)alloc((size_t)Ne * 4);
    float* loop_attr = (float*)alloc((size_t)Nn * ED * 4);
    float* scores    = (float*)alloc((size_t)Ne * 4);
    float* sscore    = (float*)alloc((size_t)Nn * 4);
    float* pooled    = (float*)alloc((size_t)Gg * H2 * 4);
    float* cnt       = (float*)alloc((size_t)Gg * 4);
    float* xlb       = (float*)alloc((size_t)Nn * H1 * 4);
    float* xrb       = (float*)alloc((size_t)Nn * H1 * 4);
    float* x1        = (float*)alloc((size_t)Nn * H1 * 4);
    unsigned short* ehi = (unsigned short*)alloc((size_t)Ne * ED * 2);
    unsigned short* elo = (unsigned short*)alloc((size_t)Ne * ED * 2);
    unsigned short* lhi = (unsigned short*)alloc((size_t)Nn * ED * 2);
    unsigned short* llo = (unsigned short*)alloc((size_t)Nn * ED * 2);
    unsigned short* w1hi = (unsigned short*)alloc((size_t)H1 * ED * 2);
    unsigned short* w1lo = (unsigned short*)alloc((size_t)H1 * ED * 2);
    unsigned short* w2hi = (unsigned short*)alloc((size_t)H2 * ED * 2);
    unsigned short* w2lo = (unsigned short*)alloc((size_t)H2 * ED * 2);

    hipMemsetAsync(deg, 0, (size_t)Nn * 4, stream);
    hipMemsetAsync(cursor, 0, (size_t)Nn * 4, stream);
    hipMemsetAsync(pooled, 0, (size_t)Gg * H2 * 4, stream);
    hipMemsetAsync(cnt, 0, (size_t)Gg * 4, stream);

    count_deg_kernel<<<(Ne + 255) / 256, 256, 0, stream>>>(edge_dst, deg);
    scan_kernel<<<1, 1024, 0, stream>>>(deg, row_start);
    scatter_kernel<<<(Ne + 255) / 256, 256, 0, stream>>>(edge_dst, row_start, cursor, perm);
    build_sd_kernel<<<(Ne + 255) / 256, 256, 0, stream>>>(perm, edge_src, edge_dst, srcv, dstv);
    loop_attr_kernel<<<(Nn * 8 + 255) / 256, 256, 0, stream>>>(row_start, perm, edge_attr, loop_attr);

    // bf16 hi/lo prep
    cvt_split_kernel<<<(Ne * 8 + 255) / 256, 256, 0, stream>>>(edge_attr, ehi, elo, Ne * 8);
    cvt_split_kernel<<<(Nn * 8 + 255) / 256, 256, 0, stream>>>(loop_attr, lhi, llo, Nn * 8);
    cvt_W_kernel<<<(H1 * ED + 255) / 256, 256, 0, stream>>>(We1, w1hi, w1lo, H1);
    cvt_W_kernel<<<(H2 * ED + 255) / 256, 256, 0, stream>>>(We2, w2hi, w2lo, H2);

    const int eb64 = (Ne + 63) / 64, nb64 = (Nn + 63) / 64;

    // ---- layer 1 ----
    gemm_bias2_kernel<<<dim3(H1 / 64, (Nn + 63) / 64, 2), 256, 0, stream>>>(
        node_attr, Wl1, bl1, xlb, Wr1, br1, xrb, Nn, DIN, H1);
    score_mfma3_kernel<H1><<<eb64, 256, 0, stream>>>(
        Ne, perm, srcv, dstv, ehi, elo, xlb, xrb, w1hi, w1lo, att1, scores);
    score_mfma3_kernel<H1><<<nb64, 256, 0, stream>>>(
        Nn, nullptr, nullptr, nullptr, lhi, llo, xlb, xrb, w1hi, w1lo, att1, sscore);
    aggregate2_kernel<H1><<<(Nn + 3) / 4, 256, 0, stream>>>(
        row_start, srcv, scores, sscore, xlb, b1, x1);

    // ---- layer 2 ----
    gemm_bias2_kernel<<<dim3(H2 / 64, (Nn + 63) / 64, 2), 256, 0, stream>>>(
        x1, Wl2, bl2, xlb, Wr2, br2, xrb, Nn, H1, H2);
    score_mfma3_kernel<H2><<<eb64, 128, 0, stream>>>(
        Ne, perm, srcv, dstv, ehi, elo, xlb, xrb, w2hi, w2lo, att2, scores);
    score_mfma3_kernel<H2><<<nb64, 128, 0, stream>>>(
        Nn, nullptr, nullptr, nullptr, lhi, llo, xlb, xrb, w2hi, w2lo, att2, sscore);
    float* x2 = x1;
    aggregate2_kernel<H2><<<(Nn + 3) / 4, 256, 0, stream>>>(
        row_start, srcv, scores, sscore, xlb, b2, x2);

    // ---- pool + head ----
    pool2_kernel<<<256, 128, 0, stream>>>(x2, batch, pooled, cnt);
    head_kernel<<<Gg, 64, 0, stream>>>(pooled, cnt, Wd1, bd1, bn_gamma, bn_beta,
                                       bn_mean, bn_var, Wd2, bd2, out);
}

// Round 8
// 844.891 us; speedup vs baseline: 1.4937x; 1.0886x over previous
//
#include <hip/hip_runtime.h>
#include <cstdint>
#include <cstddef>
#include <cmath>

// Problem constants (match reference)
constexpr int Nn = 50000;
constexpr int Ne = 500000;
constexpr int Gg = 64;
constexpr int DIN = 128, ED = 32, H1 = 256, H2 = 128, HD = 64, NOUT = 8;

typedef __attribute__((ext_vector_type(8))) short bf16x8;
typedef __attribute__((ext_vector_type(4))) float f32x4;

__device__ __forceinline__ unsigned short f2bf(float x) {
    unsigned u = __float_as_uint(x);
    u += 0x7FFFu + ((u >> 16) & 1u);
    return (unsigned short)(u >> 16);
}
__device__ __forceinline__ float bf2f(unsigned short h) {
    return __uint_as_float(((unsigned)h) << 16);
}

// ---------------- CSR build ----------------
__global__ void count_deg_kernel(const int* __restrict__ dst, int* __restrict__ deg) {
    int e = blockIdx.x * 256 + threadIdx.x;
    if (e < Ne) atomicAdd(&deg[dst[e]], 1);
}

__global__ __launch_bounds__(1024) void scan_kernel(const int* __restrict__ deg,
                                                    int* __restrict__ row_start) {
    __shared__ int part[1024];
    int t = threadIdx.x;
    const int chunk = (Nn + 1023) / 1024;
    int lo = t * chunk;
    int hi = min(lo + chunk, Nn);
    int s = 0;
    for (int i = lo; i < hi; i++) s += deg[i];
    part[t] = s;
    __syncthreads();
    for (int off = 1; off < 1024; off <<= 1) {
        int add = (t >= off) ? part[t - off] : 0;
        __syncthreads();
        part[t] += add;
        __syncthreads();
    }
    int base = (t == 0) ? 0 : part[t - 1];
    for (int i = lo; i < hi; i++) { row_start[i] = base; base += deg[i]; }
    if (t == 0) row_start[Nn] = Ne;
}

__global__ void scatter_kernel(const int* __restrict__ dst, const int* __restrict__ row_start,
                               int* __restrict__ cursor, int* __restrict__ perm) {
    int e = blockIdx.x * 256 + threadIdx.x;
    if (e < Ne) {
        int d = dst[e];
        int p = atomicAdd(&cursor[d], 1);
        perm[row_start[d] + p] = e;
    }
}

__global__ void build_sd_kernel(const int* __restrict__ perm, const int* __restrict__ src,
                                const int* __restrict__ dst,
                                int* __restrict__ srcv, int* __restrict__ dstv) {
    int j = blockIdx.x * 256 + threadIdx.x;
    if (j < Ne) {
        int e = perm[j];
        srcv[j] = src[e];
        dstv[j] = dst[e];
    }
}

// loop_attr[i] = mean of incoming edge_attr rows (self-loop fill_value='mean')
__global__ void loop_attr_kernel(const int* __restrict__ row_start, const int* __restrict__ perm,
                                 const float* __restrict__ eattr, float* __restrict__ loop_attr) {
    int tid = blockIdx.x * 256 + threadIdx.x;
    if (tid >= Nn * 8) return;
    int i = tid >> 3, q = (tid & 7) << 2;
    int r0 = row_start[i], r1 = row_start[i + 1];
    float4 s = make_float4(0.f, 0.f, 0.f, 0.f);
    for (int j = r0; j < r1; j++) {
        int e = perm[j];
        float4 v = *(const float4*)(eattr + (size_t)e * ED + q);
        s.x += v.x; s.y += v.y; s.z += v.z; s.w += v.w;
    }
    float inv = 1.0f / fmaxf((float)(r1 - r0), 1.0f);
    *(float4*)(loop_attr + (size_t)i * ED + q) =
        make_float4(s.x * inv, s.y * inv, s.z * inv, s.w * inv);
}

// ---------------- bf16 hi/lo split prep ----------------
// hi = RN_bf16(x), lo = RN_bf16(x - hi): A*B ~ AhBh + AhBl + AlBh, err ~1e-5 rel.
__global__ void cvt_split_kernel(const float* __restrict__ src,
                                 unsigned short* __restrict__ hi,
                                 unsigned short* __restrict__ lo, int n4) {
    int idx = blockIdx.x * 256 + threadIdx.x;
    if (idx >= n4) return;
    float4 v = *(const float4*)(src + (size_t)idx * 4);
    float x[4] = {v.x, v.y, v.z, v.w};
    unsigned short h[4], l[4];
#pragma unroll
    for (int c = 0; c < 4; c++) {
        h[c] = f2bf(x[c]);
        l[c] = f2bf(x[c] - bf2f(h[c]));
    }
    *(ushort4*)(hi + (size_t)idx * 4) = make_ushort4(h[0], h[1], h[2], h[3]);
    *(ushort4*)(lo + (size_t)idx * 4) = make_ushort4(l[0], l[1], l[2], l[3]);
}

// W[K][N] -> Wt[N][K] bf16 hi/lo (transposed so MFMA fragments read 16B contiguous k)
__global__ void cvt_wt_kernel(const float* __restrict__ W,
                              unsigned short* __restrict__ hi,
                              unsigned short* __restrict__ lo, int K, int N) {
    int t = blockIdx.x * 256 + threadIdx.x;
    if (t >= K * N) return;
    int col = t / K, k = t % K;
    float x = W[(size_t)k * N + col];
    unsigned short h = f2bf(x);
    hi[t] = h;
    lo[t] = f2bf(x - bf2f(h));
}

// ---------------- MFMA dense GEMM v2: C[M,N] = A[M,K] @ W[K,N] + bias --------------------
// R16 post-mortem of R7 crash: (a) materializing hi/lo activation copies (+77MB) likely
// overflowed the workspace (R5/R6's ~240MB passed; R7 ~317MB crashed with device fault);
// (b) K=256 static LDS was 67.6KB. Fix both: A is read as fp32 and hi/lo-SPLIT IN THE
// STAGING LOOP (same HBM bytes: 4B/elem either way; 4 VALU ops/elem), and K is staged in
// 128-wide chunks -> LDS fixed at 34.8KB for both layers. Zero new global buffers.
// Layout identical to the session-verified convention (score_mfma2/3, roles swapped
// consistently): A frag row=li -> node, k=g*8+j (LDS); B frag col=li -> W-col, k=g*8+j
// (global Wt[N][K], L2-hot); D row=(g*4+r) -> node, col=li -> W-col -> coalesced stores.
// Bias preloaded in fp32 C-operand. Tripwire: WRITE_SIZE ~51MB legit; >>55MB = spill.
template <int K, int N>
__global__ __launch_bounds__(256) void gemm_mfma_kernel(
    int M, const float* __restrict__ A,
    const unsigned short* __restrict__ wt0hi, const unsigned short* __restrict__ wt0lo,
    const float* __restrict__ bias0, float* __restrict__ C0,
    const unsigned short* __restrict__ wt1hi, const unsigned short* __restrict__ wt1lo,
    const float* __restrict__ bias1, float* __restrict__ C1) {
    const unsigned short* wthi = blockIdx.z ? wt1hi : wt0hi;
    const unsigned short* wtlo = blockIdx.z ? wt1lo : wt0lo;
    const float* bias = blockIdx.z ? bias1 : bias0;
    float* Cc = blockIdx.z ? C1 : C0;
    constexpr int KC = (K > 128) ? 128 : K;   // k-chunk staged in LDS
    constexpr int P = KC + 8;                 // LDS pitch (ushorts), rows 16B-aligned
    constexpr int NT = N / 64;                // n-tiles per wave (4 waves cover N)
    constexpr int CH = KC / 4;                // float4 chunks per row per k-chunk
    __shared__ unsigned short Ah[64 * P], Al[64 * P];
    const int tid = threadIdx.x;
    const int m0 = blockIdx.y * 64;

    const int wv = tid >> 6, lane = tid & 63;
    const int g = lane >> 4, li = lane & 15;
    const int nb = wv * (N / 4);              // this wave's col base

    f32x4 acc[4][NT];
#pragma unroll
    for (int n = 0; n < NT; n++) {
        float bc = bias[nb + n * 16 + li];
#pragma unroll
        for (int m = 0; m < 4; m++) {
            acc[m][n][0] = bc; acc[m][n][1] = bc; acc[m][n][2] = bc; acc[m][n][3] = bc;
        }
    }

    for (int kc = 0; kc < K; kc += KC) {
        // stage A k-chunk: 64 node rows x KC fp32 -> hi/lo bf16 in LDS (split in-flight)
        for (int t = tid; t < 64 * CH; t += 256) {
            int row = t / CH, c = t % CH;
            int gr = min(m0 + row, M - 1);
            float4 v = *(const float4*)(A + (size_t)gr * K + kc + c * 4);
            unsigned short h0 = f2bf(v.x), h1 = f2bf(v.y), h2 = f2bf(v.z), h3 = f2bf(v.w);
            unsigned short l0 = f2bf(v.x - bf2f(h0)), l1 = f2bf(v.y - bf2f(h1));
            unsigned short l2 = f2bf(v.z - bf2f(h2)), l3 = f2bf(v.w - bf2f(h3));
            *(ushort4*)&Ah[row * P + c * 4] = make_ushort4(h0, h1, h2, h3);
            *(ushort4*)&Al[row * P + c * 4] = make_ushort4(l0, l1, l2, l3);
        }
        __syncthreads();

#pragma unroll
        for (int kt = 0; kt < KC / 32; kt++) {
            bf16x8 afh[4], afl[4], bfh[NT], bfl[NT];
#pragma unroll
            for (int m = 0; m < 4; m++) {
                afh[m] = *(const bf16x8*)&Ah[(m * 16 + li) * P + kt * 32 + g * 8];
                afl[m] = *(const bf16x8*)&Al[(m * 16 + li) * P + kt * 32 + g * 8];
            }
#pragma unroll
            for (int n = 0; n < NT; n++) {
                int col = nb + n * 16 + li;
                bfh[n] = *(const bf16x8*)(wthi + (size_t)col * K + kc + kt * 32 + g * 8);
                bfl[n] = *(const bf16x8*)(wtlo + (size_t)col * K + kc + kt * 32 + g * 8);
            }
#pragma unroll
            for (int m = 0; m < 4; m++)
#pragma unroll
                for (int n = 0; n < NT; n++) {
                    acc[m][n] = __builtin_amdgcn_mfma_f32_16x16x32_bf16(afh[m], bfh[n], acc[m][n], 0, 0, 0);
                    acc[m][n] = __builtin_amdgcn_mfma_f32_16x16x32_bf16(afh[m], bfl[n], acc[m][n], 0, 0, 0);
                    acc[m][n] = __builtin_amdgcn_mfma_f32_16x16x32_bf16(afl[m], bfh[n], acc[m][n], 0, 0, 0);
                }
        }
        __syncthreads();
    }

    // coalesced dword stores: per (m,n,r) instr, 4 node rows x 16 consecutive cols
#pragma unroll
    for (int m = 0; m < 4; m++)
#pragma unroll
        for (int n = 0; n < NT; n++) {
            int col = nb + n * 16 + li;
#pragma unroll
            for (int r = 0; r < 4; r++) {
                int node = m0 + m * 16 + g * 4 + r;
                if (node < M) Cc[(size_t)node * N + col] = acc[m][n][r];
            }
        }
}

// ---------------- MFMA score kernel v3 (kept from R6; 115us, parked) ---------------------
template <int C>
__global__ __launch_bounds__((C / 64) * 64) void score_mfma3_kernel(
    int count, const int* __restrict__ perm,
    const int* __restrict__ srcv, const int* __restrict__ dstv,
    const unsigned short* __restrict__ ehi, const unsigned short* __restrict__ elo,
    const float* __restrict__ xl, const float* __restrict__ xr,
    const unsigned short* __restrict__ wthi, const unsigned short* __restrict__ wtlo,
    const float* __restrict__ att, float* __restrict__ sc_out) {
    constexpr int WPB = C / 64;          // waves per block (4 for C=256, 2 for C=128)
    constexpr int NTHR = WPB * 64;
    __shared__ unsigned short Ah[64 * 40], Al[64 * 40];  // pitch 40 ush = 80B, 16B-aligned
    __shared__ float pw[WPB][64];
    const int tid = threadIdx.x;
    const int j0 = blockIdx.x * 64;

    // stage 64 edge rows x 32 k bf16 (hi,lo) into LDS, coalesced 16B chunks
    for (int t = tid; t < 64 * 4; t += NTHR) {
        int row = t >> 2, part = t & 3;
        int j = min(j0 + row, count - 1);
        int e = perm ? perm[j] : j;
        *(uint4*)&Ah[row * 40 + part * 8] = *(const uint4*)(ehi + (size_t)e * ED + part * 8);
        *(uint4*)&Al[row * 40 + part * 8] = *(const uint4*)(elo + (size_t)e * ED + part * 8);
    }
    __syncthreads();

    const int wv = tid >> 6, lane = tid & 63;
    const int g = lane >> 4, li = lane & 15;
    const int cb = wv * 64 + g * 4;      // lane's col base (plus m*16)

    // A operand: Wt column fragments, straight from global (tiny, L1-hot)
    bf16x8 af_h[4], af_l[4];
#pragma unroll
    for (int m = 0; m < 4; m++) {
        int col = wv * 64 + m * 16 + li;
        af_h[m] = *(const bf16x8*)(wthi + (size_t)col * ED + g * 8);
        af_l[m] = *(const bf16x8*)(wtlo + (size_t)col * ED + g * 8);
    }
    float4 attv[4];
#pragma unroll
    for (int m = 0; m < 4; m++) attv[m] = *(const float4*)(att + cb + m * 16);

    // hoisted edge indices for all 4 n-tiles (scalars, no arrays -> no scratch)
    int s0, d0, s1, d1, s2, d2, s3, d3;
    {
        int j;
        j = min(j0 + 0 * 16 + li, count - 1); s0 = srcv ? srcv[j] : j; d0 = dstv ? dstv[j] : j;
        j = min(j0 + 1 * 16 + li, count - 1); s1 = srcv ? srcv[j] : j; d1 = dstv ? dstv[j] : j;
        j = min(j0 + 2 * 16 + li, count - 1); s2 = srcv ? srcv[j] : j; d2 = dstv ? dstv[j] : j;
        j = min(j0 + 3 * 16 + li, count - 1); s3 = srcv ? srcv[j] : j; d3 = dstv ? dstv[j] : j;
    }

    // prefetch: LDS B-fragments + xl/xr gathers for one tile into a named register set
    auto pf = [&](int n, int sE, int dE, bf16x8& bh, bf16x8& bl,
                  float4 (&xlv)[4], float4 (&xrv)[4]) {
        bh = *(const bf16x8*)&Ah[(n * 16 + li) * 40 + g * 8];
        bl = *(const bf16x8*)&Al[(n * 16 + li) * 40 + g * 8];
        const float* pl = xl + (size_t)sE * C + cb;
        const float* pr = xr + (size_t)dE * C + cb;
#pragma unroll
        for (int m = 0; m < 4; m++) {
            xlv[m] = *(const float4*)(pl + m * 16);
            xrv[m] = *(const float4*)(pr + m * 16);
        }
    };
    // compute: acc preload (C-op = xl+xr), 12 MFMAs, LReLU+att-dot epilogue, partial write
    auto comp = [&](int n, bf16x8 bh, bf16x8 bl,
                    const float4 (&xlv)[4], const float4 (&xrv)[4]) {
        f32x4 acc[4];
#pragma unroll
        for (int m = 0; m < 4; m++) {
            acc[m][0] = xlv[m].x + xrv[m].x; acc[m][1] = xlv[m].y + xrv[m].y;
            acc[m][2] = xlv[m].z + xrv[m].z; acc[m][3] = xlv[m].w + xrv[m].w;
        }
#pragma unroll
        for (int m = 0; m < 4; m++) {
            acc[m] = __builtin_amdgcn_mfma_f32_16x16x32_bf16(af_h[m], bh, acc[m], 0, 0, 0);
            acc[m] = __builtin_amdgcn_mfma_f32_16x16x32_bf16(af_h[m], bl, acc[m], 0, 0, 0);
            acc[m] = __builtin_amdgcn_mfma_f32_16x16x32_bf16(af_l[m], bh, acc[m], 0, 0, 0);
        }
        float s = 0.f;
#pragma unroll
        for (int m = 0; m < 4; m++) {
            const float av[4] = {attv[m].x, attv[m].y, attv[m].z, attv[m].w};
#pragma unroll
            for (int r = 0; r < 4; r++) {
                float z = acc[m][r];
                z = z > 0.f ? z : 0.2f * z;
                s = fmaf(z, av[r], s);
            }
        }
        s += __shfl_xor(s, 16);
        s += __shfl_xor(s, 32);
        if (lane < 16) pw[wv][n * 16 + li] = s;
    };

    bf16x8 bhA, blA, bhB, blB;
    float4 xlA[4], xrA[4], xlB[4], xrB[4];
    pf(0, s0, d0, bhA, blA, xlA, xrA);
    pf(1, s1, d1, bhB, blB, xlB, xrB);
    comp(0, bhA, blA, xlA, xrA);
    pf(2, s2, d2, bhA, blA, xlA, xrA);
    comp(1, bhB, blB, xlB, xrB);
    pf(3, s3, d3, bhB, blB, xlB, xrB);
    comp(2, bhA, blA, xlA, xrA);
    comp(3, bhB, blB, xlB, xrB);

    __syncthreads();
    if (tid < 64) {
        float s = pw[0][tid];
#pragma unroll
        for (int w = 1; w < WPB; w++) s += pw[w][tid];
        int j = j0 + tid;
        if (j < count) sc_out[j] = s;
    }
}

// ---------------- aggregate: softmax over precomputed scores + pipelined gather ----------
template <int C>
__global__ __launch_bounds__(256) void aggregate2_kernel(
    const int* __restrict__ row_start, const int* __restrict__ srcv,
    const float* __restrict__ scores, const float* __restrict__ sscore,
    const float* __restrict__ xl, const float* __restrict__ bias,
    float* __restrict__ xout) {
    constexpr int VP = C / 64;
    const int wave = threadIdx.x >> 6, lane = threadIdx.x & 63;
    const int i = blockIdx.x * 4 + wave;
    if (i >= Nn) return;
    const int r0 = row_start[i], r1 = row_start[i + 1];

    // max over incoming + self
    float mx = sscore[i];
    for (int j = r0 + lane; j < r1; j += 64) mx = fmaxf(mx, scores[j]);
#pragma unroll
    for (int off = 32; off >= 1; off >>= 1) mx = fmaxf(mx, __shfl_xor(mx, off));

    float l = 0.f;
    float acc[VP];
#pragma unroll
    for (int j = 0; j < VP; j++) acc[j] = 0.f;

    float wA[4], xA[4][VP];
    auto load_batch = [&](int j0, float* w, float (*x)[VP]) {
#pragma unroll
        for (int q = 0; q < 4; q++) {
            int j = min(j0 + q, r1 - 1);
            w[q] = scores[j];
            const float* p = xl + (size_t)srcv[j] * C + lane * VP;
            if constexpr (VP == 4) {
                float4 v = *(const float4*)p;
                x[q][0] = v.x; x[q][1] = v.y; x[q][2] = v.z; x[q][3] = v.w;
            } else {
                float2 v = *(const float2*)p;
                x[q][0] = v.x; x[q][1] = v.y;
            }
        }
    };
    if (r0 < r1) load_batch(r0, wA, xA);

    for (int j0 = r0; j0 < r1; j0 += 4) {
        float wB[4], xB[4][VP];
        if (j0 + 4 < r1) load_batch(j0 + 4, wB, xB);  // prefetch next batch
        const int nb = min(4, r1 - j0);
        for (int q = 0; q < nb; q++) {
            float w = __expf(wA[q] - mx);
            l += w;
#pragma unroll
            for (int j = 0; j < VP; j++) acc[j] = fmaf(w, xA[q][j], acc[j]);
        }
        if (j0 + 4 < r1) {
#pragma unroll
            for (int q = 0; q < 4; q++) {
                wA[q] = wB[q];
#pragma unroll
                for (int j = 0; j < VP; j++) xA[q][j] = xB[q][j];
            }
        }
    }

    // self-loop
    {
        float w = __expf(sscore[i] - mx);
        l += w;
        const float* p = xl + (size_t)i * C + lane * VP;
        if constexpr (VP == 4) {
            float4 v = *(const float4*)p;
            acc[0] = fmaf(w, v.x, acc[0]); acc[1] = fmaf(w, v.y, acc[1]);
            acc[2] = fmaf(w, v.z, acc[2]); acc[3] = fmaf(w, v.w, acc[3]);
        } else {
            float2 v = *(const float2*)p;
            acc[0] = fmaf(w, v.x, acc[0]); acc[1] = fmaf(w, v.y, acc[1]);
        }
    }

    float invl = 1.0f / l;
    float* xo = xout + (size_t)i * C + lane * VP;
    if constexpr (VP == 4) {
        float4 bv = *(const float4*)(bias + lane * 4);
        float4 o;
        o.x = fmaxf(fmaf(acc[0], invl, bv.x), 0.f);
        o.y = fmaxf(fmaf(acc[1], invl, bv.y), 0.f);
        o.z = fmaxf(fmaf(acc[2], invl, bv.z), 0.f);
        o.w = fmaxf(fmaf(acc[3], invl, bv.w), 0.f);
        *(float4*)xo = o;
    } else {
        float2 bv = *(const float2*)(bias + lane * 2);
        float2 o;
        o.x = fmaxf(fmaf(acc[0], invl, bv.x), 0.f);
        o.y = fmaxf(fmaf(acc[1], invl, bv.y), 0.f);
        *(float2*)xo = o;
    }
}

// ---------------- global mean pool: run-length accumulation (batch is sorted) -------------
__global__ __launch_bounds__(128) void pool2_kernel(const float* __restrict__ x2,
                                                    const int* __restrict__ batch,
                                                    float* __restrict__ pooled,
                                                    float* __restrict__ cnt) {
    const int c = threadIdx.x;  // column 0..127
    const int chunk = (Nn + gridDim.x - 1) / gridDim.x;
    int lo = blockIdx.x * chunk;
    int hi = min(lo + chunk, Nn);
    if (lo >= hi) return;
    int gcur = batch[lo];
    float acc = 0.f, ncnt = 0.f;
    for (int i = lo; i < hi; i++) {
        int g = batch[i];
        if (g != gcur) {
            atomicAdd(&pooled[gcur * H2 + c], acc);
            if (c == 0) atomicAdd(&cnt[gcur], ncnt);
            acc = 0.f; ncnt = 0.f; gcur = g;
        }
        acc += x2[(size_t)i * H2 + c];
        ncnt += 1.f;
    }
    atomicAdd(&pooled[gcur * H2 + c], acc);
    if (c == 0) atomicAdd(&cnt[gcur], ncnt);
}

// ---------------- MLP head ----------------
__global__ __launch_bounds__(64) void head_kernel(
    const float* __restrict__ pooled, const float* __restrict__ cnt,
    const float* __restrict__ Wd1, const float* __restrict__ bd1,
    const float* __restrict__ gamma, const float* __restrict__ beta,
    const float* __restrict__ mean, const float* __restrict__ var,
    const float* __restrict__ Wd2, const float* __restrict__ bd2,
    float* __restrict__ out) {
    __shared__ float xm[H2];
    __shared__ float h[HD];
    int g = blockIdx.x, t = threadIdx.x;
    float c = fmaxf(cnt[g], 1.0f);
    for (int i = t; i < H2; i += 64) xm[i] = pooled[g * H2 + i] / c;
    __syncthreads();
    float a = bd1[t];
    for (int k = 0; k < H2; k++) a = fmaf(xm[k], Wd1[k * HD + t], a);
    a = (a - mean[t]) / sqrtf(var[t] + 1e-5f) * gamma[t] + beta[t];
    a = a > 0.f ? a : 0.1f * a;
    h[t] = a;
    __syncthreads();
    if (t < NOUT) {
        float o = bd2[t];
        for (int k = 0; k < HD; k++) o = fmaf(h[k], Wd2[k * NOUT + t], o);
        out[g * NOUT + t] = o;
    }
}

extern "C" void kernel_launch(void* const* d_in, const int* in_sizes, int n_in,
                              void* d_out, int out_size, void* d_ws, size_t ws_size,
                              hipStream_t stream) {
    const float* node_attr = (const float*)d_in[0];
    const float* edge_attr = (const float*)d_in[1];
    const int* edge_src = (const int*)d_in[2];
    const int* edge_dst = (const int*)d_in[3];
    const int* batch = (const int*)d_in[4];
    const float* Wl1 = (const float*)d_in[5];  const float* bl1 = (const float*)d_in[6];
    const float* Wr1 = (const float*)d_in[7];  const float* br1 = (const float*)d_in[8];
    const float* We1 = (const float*)d_in[9];  const float* att1 = (const float*)d_in[10];
    const float* b1 = (const float*)d_in[11];
    const float* Wl2 = (const float*)d_in[12]; const float* bl2 = (const float*)d_in[13];
    const float* Wr2 = (const float*)d_in[14]; const float* br2 = (const float*)d_in[15];
    const float* We2 = (const float*)d_in[16]; const float* att2 = (const float*)d_in[17];
    const float* b2 = (const float*)d_in[18];
    const float* Wd1 = (const float*)d_in[19]; const float* bd1 = (const float*)d_in[20];
    const float* bn_gamma = (const float*)d_in[21]; const float* bn_beta = (const float*)d_in[22];
    const float* bn_mean = (const float*)d_in[23];  const float* bn_var = (const float*)d_in[24];
    const float* Wd2 = (const float*)d_in[25]; const float* bd2 = (const float*)d_in[26];
    float* out = (float*)d_out;

    char* ws = (char*)d_ws;
    size_t off = 0;
    auto alloc = [&](size_t bytes) -> char* {
        char* p = ws + off;
        off = (off + bytes + 255) & ~(size_t)255;
        return p;
    };
    int* deg         = (int*)alloc((size_t)Nn * 4);
    int* row_start   = (int*)alloc((size_t)(Nn + 1) * 4);
    int* cursor      = (int*)alloc((size_t)Nn * 4);
    int* perm        = (int*)alloc((size_t)Ne * 4);
    int* srcv        = (int*)alloc((size_t)Ne * 4);
    int* dstv        = (int*)alloc((size_t)Ne * 4);
    float* loop_attr = (float*)alloc((size_t)Nn * ED * 4);
    float* scores    = (float*)alloc((size_t)Ne * 4);
    float* sscore    = (float*)alloc((size_t)Nn * 4);
    float* pooled    = (float*)alloc((size_t)Gg * H2 * 4);
    float* cnt       = (float*)alloc((size_t)Gg * 4);
    float* xlb       = (float*)alloc((size_t)Nn * H1 * 4);
    float* xrb       = (float*)alloc((size_t)Nn * H1 * 4);
    float* x1        = (float*)alloc((size_t)Nn * H1 * 4);
    unsigned short* ehi = (unsigned short*)alloc((size_t)Ne * ED * 2);
    unsigned short* elo = (unsigned short*)alloc((size_t)Ne * ED * 2);
    unsigned short* lhi = (unsigned short*)alloc((size_t)Nn * ED * 2);
    unsigned short* llo = (unsigned short*)alloc((size_t)Nn * ED * 2);
    unsigned short* w1hi = (unsigned short*)alloc((size_t)H1 * ED * 2);
    unsigned short* w1lo = (unsigned short*)alloc((size_t)H1 * ED * 2);
    unsigned short* w2hi = (unsigned short*)alloc((size_t)H2 * ED * 2);
    unsigned short* w2lo = (unsigned short*)alloc((size_t)H2 * ED * 2);
    // dense-gemm weight splits (tiny; activations are split in-kernel now)
    unsigned short* wl1hi = (unsigned short*)alloc((size_t)H1 * DIN * 2);
    unsigned short* wl1lo = (unsigned short*)alloc((size_t)H1 * DIN * 2);
    unsigned short* wr1hi = (unsigned short*)alloc((size_t)H1 * DIN * 2);
    unsigned short* wr1lo = (unsigned short*)alloc((size_t)H1 * DIN * 2);
    unsigned short* wl2hi = (unsigned short*)alloc((size_t)H2 * H1 * 2);
    unsigned short* wl2lo = (unsigned short*)alloc((size_t)H2 * H1 * 2);
    unsigned short* wr2hi = (unsigned short*)alloc((size_t)H2 * H1 * 2);
    unsigned short* wr2lo = (unsigned short*)alloc((size_t)H2 * H1 * 2);

    hipMemsetAsync(deg, 0, (size_t)Nn * 4, stream);
    hipMemsetAsync(cursor, 0, (size_t)Nn * 4, stream);
    hipMemsetAsync(pooled, 0, (size_t)Gg * H2 * 4, stream);
    hipMemsetAsync(cnt, 0, (size_t)Gg * 4, stream);

    count_deg_kernel<<<(Ne + 255) / 256, 256, 0, stream>>>(edge_dst, deg);
    scan_kernel<<<1, 1024, 0, stream>>>(deg, row_start);
    scatter_kernel<<<(Ne + 255) / 256, 256, 0, stream>>>(edge_dst, row_start, cursor, perm);
    build_sd_kernel<<<(Ne + 255) / 256, 256, 0, stream>>>(perm, edge_src, edge_dst, srcv, dstv);
    loop_attr_kernel<<<(Nn * 8 + 255) / 256, 256, 0, stream>>>(row_start, perm, edge_attr, loop_attr);

    // bf16 hi/lo prep (edge attrs + all weight transposes; activations split in-kernel)
    cvt_split_kernel<<<(Ne * 8 + 255) / 256, 256, 0, stream>>>(edge_attr, ehi, elo, Ne * 8);
    cvt_split_kernel<<<(Nn * 8 + 255) / 256, 256, 0, stream>>>(loop_attr, lhi, llo, Nn * 8);
    cvt_wt_kernel<<<(H1 * ED + 255) / 256, 256, 0, stream>>>(We1, w1hi, w1lo, ED, H1);
    cvt_wt_kernel<<<(H2 * ED + 255) / 256, 256, 0, stream>>>(We2, w2hi, w2lo, ED, H2);
    cvt_wt_kernel<<<(DIN * H1 + 255) / 256, 256, 0, stream>>>(Wl1, wl1hi, wl1lo, DIN, H1);
    cvt_wt_kernel<<<(DIN * H1 + 255) / 256, 256, 0, stream>>>(Wr1, wr1hi, wr1lo, DIN, H1);
    cvt_wt_kernel<<<(H1 * H2 + 255) / 256, 256, 0, stream>>>(Wl2, wl2hi, wl2lo, H1, H2);
    cvt_wt_kernel<<<(H1 * H2 + 255) / 256, 256, 0, stream>>>(Wr2, wr2hi, wr2lo, H1, H2);

    const int eb64 = (Ne + 63) / 64, nb64 = (Nn + 63) / 64;
    const int gb = (Nn + 63) / 64;

    // ---- layer 1 ----
    gemm_mfma_kernel<DIN, H1><<<dim3(1, gb, 2), 256, 0, stream>>>(
        Nn, node_attr, wl1hi, wl1lo, bl1, xlb, wr1hi, wr1lo, br1, xrb);
    score_mfma3_kernel<H1><<<eb64, 256, 0, stream>>>(
        Ne, perm, srcv, dstv, ehi, elo, xlb, xrb, w1hi, w1lo, att1, scores);
    score_mfma3_kernel<H1><<<nb64, 256, 0, stream>>>(
        Nn, nullptr, nullptr, nullptr, lhi, llo, xlb, xrb, w1hi, w1lo, att1, sscore);
    aggregate2_kernel<H1><<<(Nn + 3) / 4, 256, 0, stream>>>(
        row_start, srcv, scores, sscore, xlb, b1, x1);

    // ---- layer 2 ----
    gemm_mfma_kernel<H1, H2><<<dim3(1, gb, 2), 256, 0, stream>>>(
        Nn, x1, wl2hi, wl2lo, bl2, xlb, wr2hi, wr2lo, br2, xrb);
    score_mfma3_kernel<H2><<<eb64, 128, 0, stream>>>(
        Ne, perm, srcv, dstv, ehi, elo, xlb, xrb, w2hi, w2lo, att2, scores);
    score_mfma3_kernel<H2><<<nb64, 128, 0, stream>>>(
        Nn, nullptr, nullptr, nullptr, lhi, llo, xlb, xrb, w2hi, w2lo, att2, sscore);
    float* x2 = x1;
    aggregate2_kernel<H2><<<(Nn + 3) / 4, 256, 0, stream>>>(
        row_start, srcv, scores, sscore, xlb, b2, x2);

    // ---- pool + head ----
    pool2_kernel<<<256, 128, 0, stream>>>(x2, batch, pooled, cnt);
    head_kernel<<<Gg, 64, 0, stream>>>(pooled, cnt, Wd1, bd1, bn_gamma, bn_beta,
                                       bn_mean, bn_var, Wd2, bd2, out);
}

// Round 9
// 782.606 us; speedup vs baseline: 1.6126x; 1.0796x over previous
//
#include <hip/hip_runtime.h>
#include <cstdint>
#include <cstddef>
#include <cmath>

// Problem constants (match reference)
constexpr int Nn = 50000;
constexpr int Ne = 500000;
constexpr int Gg = 64;
constexpr int DIN = 128, ED = 32, H1 = 256, H2 = 128, HD = 64, NOUT = 8;

typedef __attribute__((ext_vector_type(8))) short bf16x8;
typedef __attribute__((ext_vector_type(4))) float f32x4;

__device__ __forceinline__ unsigned short f2bf(float x) {
    unsigned u = __float_as_uint(x);
    u += 0x7FFFu + ((u >> 16) & 1u);
    return (unsigned short)(u >> 16);
}
__device__ __forceinline__ float bf2f(unsigned short h) {
    return __uint_as_float(((unsigned)h) << 16);
}

// ---------------- CSR build ----------------
__global__ void count_deg_kernel(const int* __restrict__ dst, int* __restrict__ deg) {
    int e = blockIdx.x * 256 + threadIdx.x;
    if (e < Ne) atomicAdd(&deg[dst[e]], 1);
}

__global__ __launch_bounds__(1024) void scan_kernel(const int* __restrict__ deg,
                                                    int* __restrict__ row_start) {
    __shared__ int part[1024];
    int t = threadIdx.x;
    const int chunk = (Nn + 1023) / 1024;
    int lo = t * chunk;
    int hi = min(lo + chunk, Nn);
    int s = 0;
    for (int i = lo; i < hi; i++) s += deg[i];
    part[t] = s;
    __syncthreads();
    for (int off = 1; off < 1024; off <<= 1) {
        int add = (t >= off) ? part[t - off] : 0;
        __syncthreads();
        part[t] += add;
        __syncthreads();
    }
    int base = (t == 0) ? 0 : part[t - 1];
    for (int i = lo; i < hi; i++) { row_start[i] = base; base += deg[i]; }
    if (t == 0) row_start[Nn] = Ne;
}

__global__ void scatter_kernel(const int* __restrict__ dst, const int* __restrict__ row_start,
                               int* __restrict__ cursor, int* __restrict__ perm) {
    int e = blockIdx.x * 256 + threadIdx.x;
    if (e < Ne) {
        int d = dst[e];
        int p = atomicAdd(&cursor[d], 1);
        perm[row_start[d] + p] = e;
    }
}

__global__ void build_sd_kernel(const int* __restrict__ perm, const int* __restrict__ src,
                                const int* __restrict__ dst,
                                int* __restrict__ srcv, int* __restrict__ dstv) {
    int j = blockIdx.x * 256 + threadIdx.x;
    if (j < Ne) {
        int e = perm[j];
        srcv[j] = src[e];
        dstv[j] = dst[e];
    }
}

// loop_attr[i] = mean of incoming edge_attr rows (self-loop fill_value='mean')
__global__ void loop_attr_kernel(const int* __restrict__ row_start, const int* __restrict__ perm,
                                 const float* __restrict__ eattr, float* __restrict__ loop_attr) {
    int tid = blockIdx.x * 256 + threadIdx.x;
    if (tid >= Nn * 8) return;
    int i = tid >> 3, q = (tid & 7) << 2;
    int r0 = row_start[i], r1 = row_start[i + 1];
    float4 s = make_float4(0.f, 0.f, 0.f, 0.f);
    for (int j = r0; j < r1; j++) {
        int e = perm[j];
        float4 v = *(const float4*)(eattr + (size_t)e * ED + q);
        s.x += v.x; s.y += v.y; s.z += v.z; s.w += v.w;
    }
    float inv = 1.0f / fmaxf((float)(r1 - r0), 1.0f);
    *(float4*)(loop_attr + (size_t)i * ED + q) =
        make_float4(s.x * inv, s.y * inv, s.z * inv, s.w * inv);
}

// ---------------- batched weight transpose+split: all 6 weights in ONE dispatch ----------
// R17: 27 dispatches -> 18; each graph dispatch costs ~5-10us of serialization.
// W[K][N] -> Wt[N][K] bf16 hi/lo. blockIdx.y selects which weight (block-uniform branch).
__global__ void cvt_wt6_kernel(
    const float* __restrict__ We1, unsigned short* __restrict__ w1hi, unsigned short* __restrict__ w1lo,
    const float* __restrict__ We2, unsigned short* __restrict__ w2hi, unsigned short* __restrict__ w2lo,
    const float* __restrict__ Wl1, unsigned short* __restrict__ wl1hi, unsigned short* __restrict__ wl1lo,
    const float* __restrict__ Wr1, unsigned short* __restrict__ wr1hi, unsigned short* __restrict__ wr1lo,
    const float* __restrict__ Wl2, unsigned short* __restrict__ wl2hi, unsigned short* __restrict__ wl2lo,
    const float* __restrict__ Wr2, unsigned short* __restrict__ wr2hi, unsigned short* __restrict__ wr2lo) {
    const float* W; unsigned short *hi, *lo; int K, N;
    switch (blockIdx.y) {
        case 0: W = We1; hi = w1hi;  lo = w1lo;  K = ED;  N = H1; break;
        case 1: W = We2; hi = w2hi;  lo = w2lo;  K = ED;  N = H2; break;
        case 2: W = Wl1; hi = wl1hi; lo = wl1lo; K = DIN; N = H1; break;
        case 3: W = Wr1; hi = wr1hi; lo = wr1lo; K = DIN; N = H1; break;
        case 4: W = Wl2; hi = wl2hi; lo = wl2lo; K = H1;  N = H2; break;
        default: W = Wr2; hi = wr2hi; lo = wr2lo; K = H1;  N = H2; break;
    }
    int t = blockIdx.x * 256 + threadIdx.x;
    if (t >= K * N) return;
    int col = t / K, k = t % K;
    float x = W[(size_t)k * N + col];
    unsigned short h = f2bf(x);
    hi[t] = h;
    lo[t] = f2bf(x - bf2f(h));
}

// ---------------- MFMA dense GEMM v2 (R8, passing: kept byte-identical) ------------------
template <int K, int N>
__global__ __launch_bounds__(256) void gemm_mfma_kernel(
    int M, const float* __restrict__ A,
    const unsigned short* __restrict__ wt0hi, const unsigned short* __restrict__ wt0lo,
    const float* __restrict__ bias0, float* __restrict__ C0,
    const unsigned short* __restrict__ wt1hi, const unsigned short* __restrict__ wt1lo,
    const float* __restrict__ bias1, float* __restrict__ C1) {
    const unsigned short* wthi = blockIdx.z ? wt1hi : wt0hi;
    const unsigned short* wtlo = blockIdx.z ? wt1lo : wt0lo;
    const float* bias = blockIdx.z ? bias1 : bias0;
    float* Cc = blockIdx.z ? C1 : C0;
    constexpr int KC = (K > 128) ? 128 : K;   // k-chunk staged in LDS
    constexpr int P = KC + 8;                 // LDS pitch (ushorts), rows 16B-aligned
    constexpr int NT = N / 64;                // n-tiles per wave (4 waves cover N)
    constexpr int CH = KC / 4;                // float4 chunks per row per k-chunk
    __shared__ unsigned short Ah[64 * P], Al[64 * P];
    const int tid = threadIdx.x;
    const int m0 = blockIdx.y * 64;

    const int wv = tid >> 6, lane = tid & 63;
    const int g = lane >> 4, li = lane & 15;
    const int nb = wv * (N / 4);              // this wave's col base

    f32x4 acc[4][NT];
#pragma unroll
    for (int n = 0; n < NT; n++) {
        float bc = bias[nb + n * 16 + li];
#pragma unroll
        for (int m = 0; m < 4; m++) {
            acc[m][n][0] = bc; acc[m][n][1] = bc; acc[m][n][2] = bc; acc[m][n][3] = bc;
        }
    }

    for (int kc = 0; kc < K; kc += KC) {
        // stage A k-chunk: 64 node rows x KC fp32 -> hi/lo bf16 in LDS (split in-flight)
        for (int t = tid; t < 64 * CH; t += 256) {
            int row = t / CH, c = t % CH;
            int gr = min(m0 + row, M - 1);
            float4 v = *(const float4*)(A + (size_t)gr * K + kc + c * 4);
            unsigned short h0 = f2bf(v.x), h1 = f2bf(v.y), h2 = f2bf(v.z), h3 = f2bf(v.w);
            unsigned short l0 = f2bf(v.x - bf2f(h0)), l1 = f2bf(v.y - bf2f(h1));
            unsigned short l2 = f2bf(v.z - bf2f(h2)), l3 = f2bf(v.w - bf2f(h3));
            *(ushort4*)&Ah[row * P + c * 4] = make_ushort4(h0, h1, h2, h3);
            *(ushort4*)&Al[row * P + c * 4] = make_ushort4(l0, l1, l2, l3);
        }
        __syncthreads();

#pragma unroll
        for (int kt = 0; kt < KC / 32; kt++) {
            bf16x8 afh[4], afl[4], bfh[NT], bfl[NT];
#pragma unroll
            for (int m = 0; m < 4; m++) {
                afh[m] = *(const bf16x8*)&Ah[(m * 16 + li) * P + kt * 32 + g * 8];
                afl[m] = *(const bf16x8*)&Al[(m * 16 + li) * P + kt * 32 + g * 8];
            }
#pragma unroll
            for (int n = 0; n < NT; n++) {
                int col = nb + n * 16 + li;
                bfh[n] = *(const bf16x8*)(wthi + (size_t)col * K + kc + kt * 32 + g * 8);
                bfl[n] = *(const bf16x8*)(wtlo + (size_t)col * K + kc + kt * 32 + g * 8);
            }
#pragma unroll
            for (int m = 0; m < 4; m++)
#pragma unroll
                for (int n = 0; n < NT; n++) {
                    acc[m][n] = __builtin_amdgcn_mfma_f32_16x16x32_bf16(afh[m], bfh[n], acc[m][n], 0, 0, 0);
                    acc[m][n] = __builtin_amdgcn_mfma_f32_16x16x32_bf16(afh[m], bfl[n], acc[m][n], 0, 0, 0);
                    acc[m][n] = __builtin_amdgcn_mfma_f32_16x16x32_bf16(afl[m], bfh[n], acc[m][n], 0, 0, 0);
                }
        }
        __syncthreads();
    }

    // coalesced dword stores: per (m,n,r) instr, 4 node rows x 16 consecutive cols
#pragma unroll
    for (int m = 0; m < 4; m++)
#pragma unroll
        for (int n = 0; n < NT; n++) {
            int col = nb + n * 16 + li;
#pragma unroll
            for (int r = 0; r < 4; r++) {
                int node = m0 + m * 16 + g * 4 + r;
                if (node < M) Cc[(size_t)node * N + col] = acc[m][n][r];
            }
        }
}

// ---------------- MFMA score kernel v4: fp32 in-staging split + merged self-score --------
// R17 changes vs v3 (identical math, identical fragment layout):
//  (a) eattr/loop_attr read as fp32 and hi/lo-split IN the staging loop (R16 trick) ->
//      cvt_split prep kernels deleted (-192MB conversion traffic, -2 dispatches, -141MB ws).
//      Same HBM bytes/edge either way (128B fp32 == 128B hi+lo bf16).
//  (b) edge blocks and self-loop blocks share one grid: blockIdx.x >= eblocks -> self rows
//      (block-uniform branch; saves 2 dispatches/layer's worth of launch serialization).
template <int C>
__global__ __launch_bounds__((C / 64) * 64) void score_mfma4_kernel(
    int ecount, int eblocks, const int* __restrict__ perm,
    const int* __restrict__ srcv, const int* __restrict__ dstv,
    const float* __restrict__ eattr, float* __restrict__ esc,
    int ncount, const float* __restrict__ lattr, float* __restrict__ nsc,
    const float* __restrict__ xl, const float* __restrict__ xr,
    const unsigned short* __restrict__ wthi, const unsigned short* __restrict__ wtlo,
    const float* __restrict__ att) {
    constexpr int WPB = C / 64;          // waves per block (4 for C=256, 2 for C=128)
    constexpr int NTHR = WPB * 64;
    __shared__ unsigned short Ah[64 * 40], Al[64 * 40];  // pitch 40 ush = 80B, 16B-aligned
    __shared__ float pw[WPB][64];
    const int tid = threadIdx.x;
    const bool selfp = (int)blockIdx.x >= eblocks;
    const int bid = selfp ? ((int)blockIdx.x - eblocks) : (int)blockIdx.x;
    const int count = selfp ? ncount : ecount;
    const float* attr = selfp ? lattr : eattr;
    float* sc_out = selfp ? nsc : esc;
    const int j0 = bid * 64;

    // stage 64 rows x 32 k fp32 -> hi/lo bf16 in LDS (split in-flight)
    for (int t = tid; t < 64 * 8; t += NTHR) {
        int row = t >> 3, c = t & 7;
        int j = min(j0 + row, count - 1);
        int e = selfp ? j : perm[j];
        float4 v = *(const float4*)(attr + (size_t)e * ED + c * 4);
        unsigned short h0 = f2bf(v.x), h1 = f2bf(v.y), h2 = f2bf(v.z), h3 = f2bf(v.w);
        unsigned short l0 = f2bf(v.x - bf2f(h0)), l1 = f2bf(v.y - bf2f(h1));
        unsigned short l2 = f2bf(v.z - bf2f(h2)), l3 = f2bf(v.w - bf2f(h3));
        *(ushort4*)&Ah[row * 40 + c * 4] = make_ushort4(h0, h1, h2, h3);
        *(ushort4*)&Al[row * 40 + c * 4] = make_ushort4(l0, l1, l2, l3);
    }
    __syncthreads();

    const int wv = tid >> 6, lane = tid & 63;
    const int g = lane >> 4, li = lane & 15;
    const int cb = wv * 64 + g * 4;      // lane's col base (plus m*16)

    // A operand: Wt column fragments, straight from global (tiny, L1-hot)
    bf16x8 af_h[4], af_l[4];
#pragma unroll
    for (int m = 0; m < 4; m++) {
        int col = wv * 64 + m * 16 + li;
        af_h[m] = *(const bf16x8*)(wthi + (size_t)col * ED + g * 8);
        af_l[m] = *(const bf16x8*)(wtlo + (size_t)col * ED + g * 8);
    }
    float4 attv[4];
#pragma unroll
    for (int m = 0; m < 4; m++) attv[m] = *(const float4*)(att + cb + m * 16);

    // hoisted edge indices for all 4 n-tiles (scalars, no arrays -> no scratch)
    int s0, d0, s1, d1, s2, d2, s3, d3;
    {
        int j;
        j = min(j0 + 0 * 16 + li, count - 1);
        s0 = selfp ? j : srcv[j]; d0 = selfp ? j : dstv[j];
        j = min(j0 + 1 * 16 + li, count - 1);
        s1 = selfp ? j : srcv[j]; d1 = selfp ? j : dstv[j];
        j = min(j0 + 2 * 16 + li, count - 1);
        s2 = selfp ? j : srcv[j]; d2 = selfp ? j : dstv[j];
        j = min(j0 + 3 * 16 + li, count - 1);
        s3 = selfp ? j : srcv[j]; d3 = selfp ? j : dstv[j];
    }

    // prefetch: LDS B-fragments + xl/xr gathers for one tile into a named register set
    auto pf = [&](int n, int sE, int dE, bf16x8& bh, bf16x8& bl,
                  float4 (&xlv)[4], float4 (&xrv)[4]) {
        bh = *(const bf16x8*)&Ah[(n * 16 + li) * 40 + g * 8];
        bl = *(const bf16x8*)&Al[(n * 16 + li) * 40 + g * 8];
        const float* pl = xl + (size_t)sE * C + cb;
        const float* pr = xr + (size_t)dE * C + cb;
#pragma unroll
        for (int m = 0; m < 4; m++) {
            xlv[m] = *(const float4*)(pl + m * 16);
            xrv[m] = *(const float4*)(pr + m * 16);
        }
    };
    // compute: acc preload (C-op = xl+xr), 12 MFMAs, LReLU+att-dot epilogue, partial write
    auto comp = [&](int n, bf16x8 bh, bf16x8 bl,
                    const float4 (&xlv)[4], const float4 (&xrv)[4]) {
        f32x4 acc[4];
#pragma unroll
        for (int m = 0; m < 4; m++) {
            acc[m][0] = xlv[m].x + xrv[m].x; acc[m][1] = xlv[m].y + xrv[m].y;
            acc[m][2] = xlv[m].z + xrv[m].z; acc[m][3] = xlv[m].w + xrv[m].w;
        }
#pragma unroll
        for (int m = 0; m < 4; m++) {
            acc[m] = __builtin_amdgcn_mfma_f32_16x16x32_bf16(af_h[m], bh, acc[m], 0, 0, 0);
            acc[m] = __builtin_amdgcn_mfma_f32_16x16x32_bf16(af_h[m], bl, acc[m], 0, 0, 0);
            acc[m] = __builtin_amdgcn_mfma_f32_16x16x32_bf16(af_l[m], bh, acc[m], 0, 0, 0);
        }
        float s = 0.f;
#pragma unroll
        for (int m = 0; m < 4; m++) {
            const float av[4] = {attv[m].x, attv[m].y, attv[m].z, attv[m].w};
#pragma unroll
            for (int r = 0; r < 4; r++) {
                float z = acc[m][r];
                z = z > 0.f ? z : 0.2f * z;
                s = fmaf(z, av[r], s);
            }
        }
        s += __shfl_xor(s, 16);
        s += __shfl_xor(s, 32);
        if (lane < 16) pw[wv][n * 16 + li] = s;
    };

    bf16x8 bhA, blA, bhB, blB;
    float4 xlA[4], xrA[4], xlB[4], xrB[4];
    pf(0, s0, d0, bhA, blA, xlA, xrA);
    pf(1, s1, d1, bhB, blB, xlB, xrB);
    comp(0, bhA, blA, xlA, xrA);
    pf(2, s2, d2, bhA, blA, xlA, xrA);
    comp(1, bhB, blB, xlB, xrB);
    pf(3, s3, d3, bhB, blB, xlB, xrB);
    comp(2, bhA, blA, xlA, xrA);
    comp(3, bhB, blB, xlB, xrB);

    __syncthreads();
    if (tid < 64) {
        float s = pw[0][tid];
#pragma unroll
        for (int w = 1; w < WPB; w++) s += pw[w][tid];
        int j = j0 + tid;
        if (j < count) sc_out[j] = s;
    }
}

// ---------------- aggregate: softmax over precomputed scores + pipelined gather ----------
template <int C>
__global__ __launch_bounds__(256) void aggregate2_kernel(
    const int* __restrict__ row_start, const int* __restrict__ srcv,
    const float* __restrict__ scores, const float* __restrict__ sscore,
    const float* __restrict__ xl, const float* __restrict__ bias,
    float* __restrict__ xout) {
    constexpr int VP = C / 64;
    const int wave = threadIdx.x >> 6, lane = threadIdx.x & 63;
    const int i = blockIdx.x * 4 + wave;
    if (i >= Nn) return;
    const int r0 = row_start[i], r1 = row_start[i + 1];

    // max over incoming + self
    float mx = sscore[i];
    for (int j = r0 + lane; j < r1; j += 64) mx = fmaxf(mx, scores[j]);
#pragma unroll
    for (int off = 32; off >= 1; off >>= 1) mx = fmaxf(mx, __shfl_xor(mx, off));

    float l = 0.f;
    float acc[VP];
#pragma unroll
    for (int j = 0; j < VP; j++) acc[j] = 0.f;

    float wA[4], xA[4][VP];
    auto load_batch = [&](int j0, float* w, float (*x)[VP]) {
#pragma unroll
        for (int q = 0; q < 4; q++) {
            int j = min(j0 + q, r1 - 1);
            w[q] = scores[j];
            const float* p = xl + (size_t)srcv[j] * C + lane * VP;
            if constexpr (VP == 4) {
                float4 v = *(const float4*)p;
                x[q][0] = v.x; x[q][1] = v.y; x[q][2] = v.z; x[q][3] = v.w;
            } else {
                float2 v = *(const float2*)p;
                x[q][0] = v.x; x[q][1] = v.y;
            }
        }
    };
    if (r0 < r1) load_batch(r0, wA, xA);

    for (int j0 = r0; j0 < r1; j0 += 4) {
        float wB[4], xB[4][VP];
        if (j0 + 4 < r1) load_batch(j0 + 4, wB, xB);  // prefetch next batch
        const int nb = min(4, r1 - j0);
        for (int q = 0; q < nb; q++) {
            float w = __expf(wA[q] - mx);
            l += w;
#pragma unroll
            for (int j = 0; j < VP; j++) acc[j] = fmaf(w, xA[q][j], acc[j]);
        }
        if (j0 + 4 < r1) {
#pragma unroll
            for (int q = 0; q < 4; q++) {
                wA[q] = wB[q];
#pragma unroll
                for (int j = 0; j < VP; j++) xA[q][j] = xB[q][j];
            }
        }
    }

    // self-loop
    {
        float w = __expf(sscore[i] - mx);
        l += w;
        const float* p = xl + (size_t)i * C + lane * VP;
        if constexpr (VP == 4) {
            float4 v = *(const float4*)p;
            acc[0] = fmaf(w, v.x, acc[0]); acc[1] = fmaf(w, v.y, acc[1]);
            acc[2] = fmaf(w, v.z, acc[2]); acc[3] = fmaf(w, v.w, acc[3]);
        } else {
            float2 v = *(const float2*)p;
            acc[0] = fmaf(w, v.x, acc[0]); acc[1] = fmaf(w, v.y, acc[1]);
        }
    }

    float invl = 1.0f / l;
    float* xo = xout + (size_t)i * C + lane * VP;
    if constexpr (VP == 4) {
        float4 bv = *(const float4*)(bias + lane * 4);
        float4 o;
        o.x = fmaxf(fmaf(acc[0], invl, bv.x), 0.f);
        o.y = fmaxf(fmaf(acc[1], invl, bv.y), 0.f);
        o.z = fmaxf(fmaf(acc[2], invl, bv.z), 0.f);
        o.w = fmaxf(fmaf(acc[3], invl, bv.w), 0.f);
        *(float4*)xo = o;
    } else {
        float2 bv = *(const float2*)(bias + lane * 2);
        float2 o;
        o.x = fmaxf(fmaf(acc[0], invl, bv.x), 0.f);
        o.y = fmaxf(fmaf(acc[1], invl, bv.y), 0.f);
        *(float2*)xo = o;
    }
}

// ---------------- global mean pool: run-length accumulation (batch is sorted) -------------
__global__ __launch_bounds__(128) void pool2_kernel(const float* __restrict__ x2,
                                                    const int* __restrict__ batch,
                                                    float* __restrict__ pooled,
                                                    float* __restrict__ cnt) {
    const int c = threadIdx.x;  // column 0..127
    const int chunk = (Nn + gridDim.x - 1) / gridDim.x;
    int lo = blockIdx.x * chunk;
    int hi = min(lo + chunk, Nn);
    if (lo >= hi) return;
    int gcur = batch[lo];
    float acc = 0.f, ncnt = 0.f;
    for (int i = lo; i < hi; i++) {
        int g = batch[i];
        if (g != gcur) {
            atomicAdd(&pooled[gcur * H2 + c], acc);
            if (c == 0) atomicAdd(&cnt[gcur], ncnt);
            acc = 0.f; ncnt = 0.f; gcur = g;
        }
        acc += x2[(size_t)i * H2 + c];
        ncnt += 1.f;
    }
    atomicAdd(&pooled[gcur * H2 + c], acc);
    if (c == 0) atomicAdd(&cnt[gcur], ncnt);
}

// ---------------- MLP head ----------------
__global__ __launch_bounds__(64) void head_kernel(
    const float* __restrict__ pooled, const float* __restrict__ cnt,
    const float* __restrict__ Wd1, const float* __restrict__ bd1,
    const float* __restrict__ gamma, const float* __restrict__ beta,
    const float* __restrict__ mean, const float* __restrict__ var,
    const float* __restrict__ Wd2, const float* __restrict__ bd2,
    float* __restrict__ out) {
    __shared__ float xm[H2];
    __shared__ float h[HD];
    int g = blockIdx.x, t = threadIdx.x;
    float c = fmaxf(cnt[g], 1.0f);
    for (int i = t; i < H2; i += 64) xm[i] = pooled[g * H2 + i] / c;
    __syncthreads();
    float a = bd1[t];
    for (int k = 0; k < H2; k++) a = fmaf(xm[k], Wd1[k * HD + t], a);
    a = (a - mean[t]) / sqrtf(var[t] + 1e-5f) * gamma[t] + beta[t];
    a = a > 0.f ? a : 0.1f * a;
    h[t] = a;
    __syncthreads();
    if (t < NOUT) {
        float o = bd2[t];
        for (int k = 0; k < HD; k++) o = fmaf(h[k], Wd2[k * NOUT + t], o);
        out[g * NOUT + t] = o;
    }
}

extern "C" void kernel_launch(void* const* d_in, const int* in_sizes, int n_in,
                              void* d_out, int out_size, void* d_ws, size_t ws_size,
                              hipStream_t stream) {
    const float* node_attr = (const float*)d_in[0];
    const float* edge_attr = (const float*)d_in[1];
    const int* edge_src = (const int*)d_in[2];
    const int* edge_dst = (const int*)d_in[3];
    const int* batch = (const int*)d_in[4];
    const float* Wl1 = (const float*)d_in[5];  const float* bl1 = (const float*)d_in[6];
    const float* Wr1 = (const float*)d_in[7];  const float* br1 = (const float*)d_in[8];
    const float* We1 = (const float*)d_in[9];  const float* att1 = (const float*)d_in[10];
    const float* b1 = (const float*)d_in[11];
    const float* Wl2 = (const float*)d_in[12]; const float* bl2 = (const float*)d_in[13];
    const float* Wr2 = (const float*)d_in[14]; const float* br2 = (const float*)d_in[15];
    const float* We2 = (const float*)d_in[16]; const float* att2 = (const float*)d_in[17];
    const float* b2 = (const float*)d_in[18];
    const float* Wd1 = (const float*)d_in[19]; const float* bd1 = (const float*)d_in[20];
    const float* bn_gamma = (const float*)d_in[21]; const float* bn_beta = (const float*)d_in[22];
    const float* bn_mean = (const float*)d_in[23];  const float* bn_var = (const float*)d_in[24];
    const float* Wd2 = (const float*)d_in[25]; const float* bd2 = (const float*)d_in[26];
    float* out = (float*)d_out;

    char* ws = (char*)d_ws;
    size_t off = 0;
    auto alloc = [&](size_t bytes) -> char* {
        char* p = ws + off;
        off = (off + bytes + 255) & ~(size_t)255;
        return p;
    };
    int* deg         = (int*)alloc((size_t)Nn * 4);
    int* row_start   = (int*)alloc((size_t)(Nn + 1) * 4);
    int* cursor      = (int*)alloc((size_t)Nn * 4);
    int* perm        = (int*)alloc((size_t)Ne * 4);
    int* srcv        = (int*)alloc((size_t)Ne * 4);
    int* dstv        = (int*)alloc((size_t)Ne * 4);
    float* loop_attr = (float*)alloc((size_t)Nn * ED * 4);
    float* scores    = (float*)alloc((size_t)Ne * 4);
    float* sscore    = (float*)alloc((size_t)Nn * 4);
    float* pooled    = (float*)alloc((size_t)Gg * H2 * 4);
    float* cnt       = (float*)alloc((size_t)Gg * 4);
    float* xlb       = (float*)alloc((size_t)Nn * H1 * 4);
    float* xrb       = (float*)alloc((size_t)Nn * H1 * 4);
    float* x1        = (float*)alloc((size_t)Nn * H1 * 4);
    // weight splits (all tiny; activations + edge attrs split in-kernel now)
    unsigned short* w1hi = (unsigned short*)alloc((size_t)H1 * ED * 2);
    unsigned short* w1lo = (unsigned short*)alloc((size_t)H1 * ED * 2);
    unsigned short* w2hi = (unsigned short*)alloc((size_t)H2 * ED * 2);
    unsigned short* w2lo = (unsigned short*)alloc((size_t)H2 * ED * 2);
    unsigned short* wl1hi = (unsigned short*)alloc((size_t)H1 * DIN * 2);
    unsigned short* wl1lo = (unsigned short*)alloc((size_t)H1 * DIN * 2);
    unsigned short* wr1hi = (unsigned short*)alloc((size_t)H1 * DIN * 2);
    unsigned short* wr1lo = (unsigned short*)alloc((size_t)H1 * DIN * 2);
    unsigned short* wl2hi = (unsigned short*)alloc((size_t)H2 * H1 * 2);
    unsigned short* wl2lo = (unsigned short*)alloc((size_t)H2 * H1 * 2);
    unsigned short* wr2hi = (unsigned short*)alloc((size_t)H2 * H1 * 2);
    unsigned short* wr2lo = (unsigned short*)alloc((size_t)H2 * H1 * 2);

    hipMemsetAsync(deg, 0, (size_t)Nn * 4, stream);
    hipMemsetAsync(cursor, 0, (size_t)Nn * 4, stream);
    hipMemsetAsync(pooled, 0, (size_t)Gg * H2 * 4, stream);
    hipMemsetAsync(cnt, 0, (size_t)Gg * 4, stream);

    count_deg_kernel<<<(Ne + 255) / 256, 256, 0, stream>>>(edge_dst, deg);
    scan_kernel<<<1, 1024, 0, stream>>>(deg, row_start);
    scatter_kernel<<<(Ne + 255) / 256, 256, 0, stream>>>(edge_dst, row_start, cursor, perm);
    build_sd_kernel<<<(Ne + 255) / 256, 256, 0, stream>>>(perm, edge_src, edge_dst, srcv, dstv);
    loop_attr_kernel<<<(Nn * 8 + 255) / 256, 256, 0, stream>>>(row_start, perm, edge_attr, loop_attr);

    // all 6 weight transposes+splits in one dispatch
    cvt_wt6_kernel<<<dim3((DIN * H1 + 255) / 256, 6), 256, 0, stream>>>(
        We1, w1hi, w1lo, We2, w2hi, w2lo, Wl1, wl1hi, wl1lo,
        Wr1, wr1hi, wr1lo, Wl2, wl2hi, wl2lo, Wr2, wr2hi, wr2lo);

    const int eb64 = (Ne + 63) / 64, nb64 = (Nn + 63) / 64;
    const int gb = (Nn + 63) / 64;

    // ---- layer 1 ----
    gemm_mfma_kernel<DIN, H1><<<dim3(1, gb, 2), 256, 0, stream>>>(
        Nn, node_attr, wl1hi, wl1lo, bl1, xlb, wr1hi, wr1lo, br1, xrb);
    score_mfma4_kernel<H1><<<eb64 + nb64, 256, 0, stream>>>(
        Ne, eb64, perm, srcv, dstv, edge_attr, scores,
        Nn, loop_attr, sscore, xlb, xrb, w1hi, w1lo, att1);
    aggregate2_kernel<H1><<<(Nn + 3) / 4, 256, 0, stream>>>(
        row_start, srcv, scores, sscore, xlb, b1, x1);

    // ---- layer 2 ----
    gemm_mfma_kernel<H1, H2><<<dim3(1, gb, 2), 256, 0, stream>>>(
        Nn, x1, wl2hi, wl2lo, bl2, xlb, wr2hi, wr2lo, br2, xrb);
    score_mfma4_kernel<H2><<<eb64 + nb64, 128, 0, stream>>>(
        Ne, eb64, perm, srcv, dstv, edge_attr, scores,
        Nn, loop_attr, sscore, xlb, xrb, w2hi, w2lo, att2);
    float* x2 = x1;
    aggregate2_kernel<H2><<<(Nn + 3) / 4, 256, 0, stream>>>(
        row_start, srcv, scores, sscore, xlb, b2, x2);

    // ---- pool + head ----
    pool2_kernel<<<256, 128, 0, stream>>>(x2, batch, pooled, cnt);
    head_kernel<<<Gg, 64, 0, stream>>>(pooled, cnt, Wd1, bd1, bn_gamma, bn_beta,
                                       bn_mean, bn_var, Wd2, bd2, out);
}